// Round 3
// baseline (7583.067 us; speedup 1.0000x reference)
//
#include <hip/hip_runtime.h>
#include <hip/hip_bf16.h>
#include <math.h>

#define T_TOK   2048
#define D_MODEL 2048
#define NHEADS  16
#define DNOPE   128
#define DROPE   64
#define DVDIM   128
#define RQ_     1536
#define RKV_    512
#define EPS_    1e-6f
#define THETA_  10000.0f

// ---------------- block-wide reduce (256 threads = 4 waves) ----------------
__device__ inline float block_reduce(float v, bool is_max, float* sred) {
    #pragma unroll
    for (int off = 32; off > 0; off >>= 1) {
        float o = __shfl_down(v, off, 64);
        v = is_max ? fmaxf(v, o) : (v + o);
    }
    int tid = threadIdx.x;
    __syncthreads();                      // protect sred reuse across calls
    if ((tid & 63) == 0) sred[tid >> 6] = v;
    __syncthreads();
    float r = sred[0];
    #pragma unroll
    for (int w = 1; w < 4; ++w) r = is_max ? fmaxf(r, sred[w]) : (r + sred[w]);
    return r;
}

// --------- generic fp32 tiled GEMM: C[M,N] = A[M,K](lda) * B[K,N](ldb) -----
__global__ __launch_bounds__(256) void gemm_f32(const float* __restrict__ A,
    const float* __restrict__ B, float* __restrict__ C,
    int M, int N, int K, int lda, int ldb, int ldc)
{
    __shared__ float As[16][65];
    __shared__ float Bs[16][64];
    int row0 = blockIdx.y * 64;
    int col0 = blockIdx.x * 64;
    int tid  = threadIdx.x;
    int tx = tid & 15, ty = tid >> 4;
    float acc[4][4] = {};
    for (int k0 = 0; k0 < K; k0 += 16) {
        #pragma unroll
        for (int i = tid; i < 64 * 16; i += 256) {
            int r = i >> 4, c = i & 15;
            As[c][r] = A[(size_t)(row0 + r) * lda + k0 + c];
        }
        #pragma unroll
        for (int i = tid; i < 16 * 64; i += 256) {
            int r = i >> 6, c = i & 63;
            Bs[r][c] = B[(size_t)(k0 + r) * ldb + col0 + c];
        }
        __syncthreads();
        #pragma unroll
        for (int kk = 0; kk < 16; ++kk) {
            float a[4], b[4];
            #pragma unroll
            for (int i = 0; i < 4; ++i) a[i] = As[kk][ty * 4 + i];
            #pragma unroll
            for (int j = 0; j < 4; ++j) b[j] = Bs[kk][tx * 4 + j];
            #pragma unroll
            for (int i = 0; i < 4; ++i)
                #pragma unroll
                for (int j = 0; j < 4; ++j)
                    acc[i][j] = fmaf(a[i], b[j], acc[i][j]);
        }
        __syncthreads();
    }
    for (int i = 0; i < 4; ++i)
        for (int j = 0; j < 4; ++j)
            C[(size_t)(row0 + ty * 4 + i) * ldc + col0 + tx * 4 + j] = acc[i][j];
}

// ---------------- in-place row RMSNorm ----------------
__global__ __launch_bounds__(256) void rmsnorm_rows(float* __restrict__ y,
    const float* __restrict__ g, int width)
{
    __shared__ float sred[4];
    int row = blockIdx.x;
    float* p = y + (size_t)row * width;
    float ss = 0.f;
    for (int i = threadIdx.x; i < width; i += 256) { float v = p[i]; ss += v * v; }
    ss = block_reduce(ss, false, sred);
    float scale = rsqrtf(ss / (float)width + EPS_);
    for (int i = threadIdx.x; i < width; i += 256) p[i] = p[i] * scale * g[i];
}

// ------- kv row: rmsnorm first 512 cols (in place) + RoPE cols 512..575 -----
__global__ __launch_bounds__(256) void kv_fuse(float* __restrict__ kv,
    const float* __restrict__ g, const int* __restrict__ positions)
{
    __shared__ float sred[4];
    int row = blockIdx.x;
    float* p = kv + (size_t)row * 576;
    float ss = 0.f;
    for (int i = threadIdx.x; i < 512; i += 256) { float v = p[i]; ss += v * v; }
    ss = block_reduce(ss, false, sred);
    float scale = rsqrtf(ss / 512.0f + EPS_);
    for (int i = threadIdx.x; i < 512; i += 256) p[i] = p[i] * scale * g[i];
    if (threadIdx.x < 32) {
        int i = threadIdx.x;
        float pos = (float)positions[row];
        float inv = powf(THETA_, -(float)i / 32.0f);
        float ang = pos * inv;
        float c = cosf(ang), s = sinf(ang);
        float x1 = p[512 + i], x2 = p[544 + i];
        p[512 + i] = x1 * c - x2 * s;
        p[544 + i] = x2 * c + x1 * s;
    }
}

// ---------------- RoPE on q_pe, in place ----------------
__global__ __launch_bounds__(256) void rope_q(float* __restrict__ q,
    const int* __restrict__ positions)
{
    int id = blockIdx.x * 256 + threadIdx.x;   // T*N*32 total
    int i = id & 31;
    int n = (id >> 5) & 15;
    int t = id >> 9;
    float* p = q + (size_t)t * 3072 + n * 192 + 128;
    float pos = (float)positions[t];
    float inv = powf(THETA_, -(float)i / 32.0f);
    float ang = pos * inv;
    float c = cosf(ang), s = sinf(ang);
    float x1 = p[i], x2 = p[32 + i];
    p[i]      = x1 * c - x2 * s;
    p[32 + i] = x2 * c + x1 * s;
}

// ---------------- attention: one workgroup per (t, head) ----------------
__global__ __launch_bounds__(256) void attn_kernel(const float* __restrict__ q,
    const float* __restrict__ kvb, const float* __restrict__ kv,
    float* __restrict__ out)
{
    __shared__ __align__(16) float qs[192];
    __shared__ float sc[2048];
    __shared__ float sred[4];
    int t = blockIdx.x, n = blockIdx.y;
    int tid = threadIdx.x;
    if (tid < 192) qs[tid] = q[(size_t)t * 3072 + n * 192 + tid];
    __syncthreads();
    int len = t + 1;
    const float scale = 0.07216878364870323f;  // 192^-0.5
    for (int s = tid; s < len; s += 256) {
        const float4* kn4 = reinterpret_cast<const float4*>(kvb + ((size_t)s * 16 + n) * 256);
        const float4* kp4 = reinterpret_cast<const float4*>(kv + (size_t)s * 576 + 512);
        const float4* qs4 = reinterpret_cast<const float4*>(qs);
        float acc = 0.f;
        #pragma unroll
        for (int h = 0; h < 32; ++h) {
            float4 a = qs4[h], b = kn4[h];
            acc += a.x * b.x + a.y * b.y + a.z * b.z + a.w * b.w;
        }
        #pragma unroll
        for (int h = 0; h < 16; ++h) {
            float4 a = qs4[32 + h], b = kp4[h];
            acc += a.x * b.x + a.y * b.y + a.z * b.z + a.w * b.w;
        }
        sc[s] = acc * scale;
    }
    __syncthreads();
    float m = -3.4e38f;
    for (int s = tid; s < len; s += 256) m = fmaxf(m, sc[s]);
    m = block_reduce(m, true, sred);
    float l = 0.f;
    for (int s = tid; s < len; s += 256) { float e = __expf(sc[s] - m); sc[s] = e; l += e; }
    l = block_reduce(l, false, sred);
    float invl = 1.0f / l;
    // PV: threads 0..127 -> even s, 128..255 -> odd s, dv = tid & 127
    int dv = tid & 127, part = tid >> 7;
    float o = 0.f;
    for (int s = part; s < len; s += 2)
        o = fmaf(sc[s], kvb[((size_t)s * 16 + n) * 256 + 128 + dv], o);
    __syncthreads();
    if (part == 0) sc[dv] = o;
    __syncthreads();
    if (part == 1) out[(size_t)t * 2048 + n * 128 + dv] = (sc[dv] + o) * invl;
}

extern "C" void kernel_launch(void* const* d_in, const int* in_sizes, int n_in,
                              void* d_out, int out_size, void* d_ws, size_t ws_size,
                              hipStream_t stream)
{
    const float* x         = (const float*)d_in[0];
    const int*   positions = (const int*)  d_in[1];
    const float* w_q_a     = (const float*)d_in[2];
    const float* q_a_norm  = (const float*)d_in[3];
    const float* w_q_b     = (const float*)d_in[4];
    const float* w_kv_a    = (const float*)d_in[5];
    const float* kv_a_norm = (const float*)d_in[6];
    const float* w_kv_b    = (const float*)d_in[7];
    const float* w_o       = (const float*)d_in[8];
    float* out = (float*)d_out;

    float* ws       = (float*)d_ws;
    float* q_c      = ws;                               // T*1536
    float* q        = q_c + (size_t)T_TOK * RQ_;        // T*3072
    float* kv       = q   + (size_t)T_TOK * 3072;       // T*576
    float* kvb      = kv  + (size_t)T_TOK * 576;        // T*4096
    float* attn_out = kvb + (size_t)T_TOK * 4096;       // T*2048

    dim3 blk(256);

    // q_c = rmsnorm(x @ w_q_a)
    gemm_f32<<<dim3(RQ_ / 64, T_TOK / 64), blk, 0, stream>>>(
        x, w_q_a, q_c, T_TOK, RQ_, D_MODEL, D_MODEL, RQ_, RQ_);
    rmsnorm_rows<<<T_TOK, blk, 0, stream>>>(q_c, q_a_norm, RQ_);

    // q = q_c @ w_q_b ; rope q_pe
    gemm_f32<<<dim3(3072 / 64, T_TOK / 64), blk, 0, stream>>>(
        q_c, w_q_b, q, T_TOK, 3072, RQ_, RQ_, 3072, 3072);
    rope_q<<<(T_TOK * NHEADS * 32) / 256, blk, 0, stream>>>(q, positions);

    // kv = x @ w_kv_a ; rmsnorm kv_c ; rope k_pe
    gemm_f32<<<dim3(576 / 64, T_TOK / 64), blk, 0, stream>>>(
        x, w_kv_a, kv, T_TOK, 576, D_MODEL, D_MODEL, 576, 576);
    kv_fuse<<<T_TOK, blk, 0, stream>>>(kv, kv_a_norm, positions);

    // kvb = kv_c @ w_kv_b   (A has row stride 576, K = 512)
    gemm_f32<<<dim3(4096 / 64, T_TOK / 64), blk, 0, stream>>>(
        kv, w_kv_b, kvb, T_TOK, 4096, RKV_, 576, 4096, 4096);

    // attention
    attn_kernel<<<dim3(T_TOK, NHEADS), blk, 0, stream>>>(q, kvb, kv, attn_out);

    // out = attn_out @ w_o
    gemm_f32<<<dim3(D_MODEL / 64, T_TOK / 64), blk, 0, stream>>>(
        attn_out, w_o, out, T_TOK, D_MODEL, NHEADS * DVDIM, 2048, D_MODEL, D_MODEL);
}

// Round 4
// 1726.169 us; speedup vs baseline: 4.3930x; 4.3930x over previous
//
#include <hip/hip_runtime.h>
#include <hip/hip_bf16.h>
#include <math.h>

#define T_TOK   2048
#define D_MODEL 2048
#define NHEADS  16
#define DNOPE   128
#define DROPE   64
#define DVDIM   128
#define RQ_     1536
#define RKV_    512
#define EPS_    1e-6f
#define THETA_  10000.0f

typedef __attribute__((ext_vector_type(8))) short short8v;
typedef __attribute__((ext_vector_type(4))) float f32x4;

__device__ inline unsigned short f2bf(float f) {
    union { float f; unsigned u; } v; v.f = f;
    unsigned r = v.u + 0x7fffu + ((v.u >> 16) & 1u);
    return (unsigned short)(r >> 16);
}

// ---------------- block-wide reduce (256 threads = 4 waves) ----------------
__device__ inline float block_reduce(float v, bool is_max, float* sred) {
    #pragma unroll
    for (int off = 32; off > 0; off >>= 1) {
        float o = __shfl_down(v, off, 64);
        v = is_max ? fmaxf(v, o) : (v + o);
    }
    int tid = threadIdx.x;
    __syncthreads();
    if ((tid & 63) == 0) sred[tid >> 6] = v;
    __syncthreads();
    float r = sred[0];
    #pragma unroll
    for (int w = 1; w < 4; ++w) r = is_max ? fmaxf(r, sred[w]) : (r + sred[w]);
    return r;
}

// --------- generic fp32 tiled GEMM: C[M,N] = A[M,K](lda) * B[K,N](ldb) -----
__global__ __launch_bounds__(256) void gemm_f32(const float* __restrict__ A,
    const float* __restrict__ B, float* __restrict__ C,
    int M, int N, int K, int lda, int ldb, int ldc)
{
    __shared__ float As[16][65];
    __shared__ float Bs[16][64];
    int row0 = blockIdx.y * 64;
    int col0 = blockIdx.x * 64;
    int tid  = threadIdx.x;
    int tx = tid & 15, ty = tid >> 4;
    float acc[4][4] = {};
    for (int k0 = 0; k0 < K; k0 += 16) {
        #pragma unroll
        for (int i = tid; i < 64 * 16; i += 256) {
            int r = i >> 4, c = i & 15;
            As[c][r] = A[(size_t)(row0 + r) * lda + k0 + c];
        }
        #pragma unroll
        for (int i = tid; i < 16 * 64; i += 256) {
            int r = i >> 6, c = i & 63;
            Bs[r][c] = B[(size_t)(k0 + r) * ldb + col0 + c];
        }
        __syncthreads();
        #pragma unroll
        for (int kk = 0; kk < 16; ++kk) {
            float a[4], b[4];
            #pragma unroll
            for (int i = 0; i < 4; ++i) a[i] = As[kk][ty * 4 + i];
            #pragma unroll
            for (int j = 0; j < 4; ++j) b[j] = Bs[kk][tx * 4 + j];
            #pragma unroll
            for (int i = 0; i < 4; ++i)
                #pragma unroll
                for (int j = 0; j < 4; ++j)
                    acc[i][j] = fmaf(a[i], b[j], acc[i][j]);
        }
        __syncthreads();
    }
    for (int i = 0; i < 4; ++i)
        for (int j = 0; j < 4; ++j)
            C[(size_t)(row0 + ty * 4 + i) * ldc + col0 + tx * 4 + j] = acc[i][j];
}

// ---------------- in-place row RMSNorm ----------------
__global__ __launch_bounds__(256) void rmsnorm_rows(float* __restrict__ y,
    const float* __restrict__ g, int width)
{
    __shared__ float sred[4];
    int row = blockIdx.x;
    float* p = y + (size_t)row * width;
    float ss = 0.f;
    for (int i = threadIdx.x; i < width; i += 256) { float v = p[i]; ss += v * v; }
    ss = block_reduce(ss, false, sred);
    float scale = rsqrtf(ss / (float)width + EPS_);
    for (int i = threadIdx.x; i < width; i += 256) p[i] = p[i] * scale * g[i];
}

// ------- kv row: rmsnorm first 512 cols (in place) + RoPE cols 512..575 -----
__global__ __launch_bounds__(256) void kv_fuse(float* __restrict__ kv,
    const float* __restrict__ g, const int* __restrict__ positions)
{
    __shared__ float sred[4];
    int row = blockIdx.x;
    float* p = kv + (size_t)row * 576;
    float ss = 0.f;
    for (int i = threadIdx.x; i < 512; i += 256) { float v = p[i]; ss += v * v; }
    ss = block_reduce(ss, false, sred);
    float scale = rsqrtf(ss / 512.0f + EPS_);
    for (int i = threadIdx.x; i < 512; i += 256) p[i] = p[i] * scale * g[i];
    if (threadIdx.x < 32) {
        int i = threadIdx.x;
        float pos = (float)positions[row];
        float inv = powf(THETA_, -(float)i / 32.0f);
        float ang = pos * inv;
        float c = cosf(ang), s = sinf(ang);
        float x1 = p[512 + i], x2 = p[544 + i];
        p[512 + i] = x1 * c - x2 * s;
        p[544 + i] = x2 * c + x1 * s;
    }
}

// ---------------- RoPE on q_pe, in place ----------------
__global__ __launch_bounds__(256) void rope_q(float* __restrict__ q,
    const int* __restrict__ positions)
{
    int id = blockIdx.x * 256 + threadIdx.x;   // T*N*32 total
    int i = id & 31;
    int n = (id >> 5) & 15;
    int t = id >> 9;
    float* p = q + (size_t)t * 3072 + n * 192 + 128;
    float pos = (float)positions[t];
    float inv = powf(THETA_, -(float)i / 32.0f);
    float ang = pos * inv;
    float c = cosf(ang), s = sinf(ang);
    float x1 = p[i], x2 = p[32 + i];
    p[i]      = x1 * c - x2 * s;
    p[32 + i] = x2 * c + x1 * s;
}

// =================== MFMA flash attention ===================
// grid (32 q-tiles, 16 heads), 256 threads = 4 waves; wave w owns q rows
// [qt*64 + w*16, +16). KV tiles of 64 keys staged in LDS (bf16, XOR-swizzled).
#define QBLK  64
#define KVBLK 64

__global__ __launch_bounds__(256) void attn_mfma(
    const float* __restrict__ q,     // [T][16*192]
    const float* __restrict__ kvb,   // [T][16][256] (0:128 k_nope, 128:256 v)
    const float* __restrict__ kv,    // [T][576]     (512:576 k_pe)
    float* __restrict__ out)         // [T][2048]
{
    __shared__ __align__(16) unsigned short Ks[KVBLK * 192];   // 24 KB
    __shared__ __align__(16) unsigned short Vt[128 * KVBLK];   // 16 KB
    __shared__ __align__(16) unsigned short Ps[4][16 * KVBLK]; //  8 KB

    const int qt = blockIdx.x, n = blockIdx.y;
    const int tid = threadIdx.x;
    const int lane = tid & 63, wid = tid >> 6;
    const int lrow = lane & 15;   // fragment row/col
    const int lkg  = lane >> 4;   // k-group
    const int q0 = qt * QBLK;
    const float scale = 0.07216878364870323f;  // (128+64)^-0.5

    // ---- Q fragments in registers (scale folded in) ----
    short8v qf[6];
    {
        const float* qrow = q + (size_t)(q0 + wid * 16 + lrow) * 3072 + n * 192;
        #pragma unroll
        for (int ds = 0; ds < 6; ++ds) {
            int d = ds * 32 + lkg * 8;
            float4 a = *(const float4*)(qrow + d);
            float4 b = *(const float4*)(qrow + d + 4);
            short8v f;
            f[0] = f2bf(a.x * scale); f[1] = f2bf(a.y * scale);
            f[2] = f2bf(a.z * scale); f[3] = f2bf(a.w * scale);
            f[4] = f2bf(b.x * scale); f[5] = f2bf(b.y * scale);
            f[6] = f2bf(b.z * scale); f[7] = f2bf(b.w * scale);
            qf[ds] = f;
        }
    }

    f32x4 oacc[8];
    #pragma unroll
    for (int i = 0; i < 8; ++i) oacc[i] = (f32x4)0.f;
    float mrow[4] = {-3e38f, -3e38f, -3e38f, -3e38f};
    float lsum[4] = {0.f, 0.f, 0.f, 0.f};

    const int ntiles = qt + 1;
    for (int tile = 0; tile < ntiles; ++tile) {
        const int s0 = tile * KVBLK;
        __syncthreads();  // previous iter's LDS reads done before restaging

        // ---- stage K tile [64 keys][192 d] bf16, swizzled ----
        for (int i4 = tid; i4 < 64 * 48; i4 += 256) {
            int row = i4 / 48, c4 = i4 % 48;
            float4 v;
            if (c4 < 32) v = *(const float4*)(kvb + ((size_t)(s0 + row) * 16 + n) * 256 + c4 * 4);
            else         v = *(const float4*)(kv + (size_t)(s0 + row) * 576 + 512 + (c4 - 32) * 4);
            unsigned lo = (unsigned)f2bf(v.x) | ((unsigned)f2bf(v.y) << 16);
            unsigned hi = (unsigned)f2bf(v.z) | ((unsigned)f2bf(v.w) << 16);
            int byte = (row * 192 + c4 * 4) * 2;
            byte ^= (row & 7) << 4;
            *(uint2*)((char*)Ks + byte) = make_uint2(lo, hi);
        }
        // ---- stage V^T [128 dv][64 s] bf16, swizzled ----
        for (int i4 = tid; i4 < 64 * 32; i4 += 256) {
            int s = i4 / 32, d4 = (i4 % 32) * 4;
            float4 v = *(const float4*)(kvb + ((size_t)(s0 + s) * 16 + n) * 256 + 128 + d4);
            #pragma unroll
            for (int e = 0; e < 4; ++e) {
                int dv = d4 + e;
                int byte = ((dv * 64 + s) * 2) ^ ((dv & 7) << 4);
                *(unsigned short*)((char*)Vt + byte) = f2bf(((const float*)&v)[e]);
            }
        }
        __syncthreads();

        // ---- S = Q K^T : 4 col-tiles x 6 d-steps ----
        f32x4 sacc[4];
        #pragma unroll
        for (int ct = 0; ct < 4; ++ct) sacc[ct] = (f32x4)0.f;
        #pragma unroll
        for (int ds = 0; ds < 6; ++ds) {
            #pragma unroll
            for (int ct = 0; ct < 4; ++ct) {
                int krow = ct * 16 + lrow;
                int byte = ((krow * 192 + ds * 32 + lkg * 8) * 2) ^ ((krow & 7) << 4);
                short8v bf = *(const short8v*)((char*)Ks + byte);
                sacc[ct] = __builtin_amdgcn_mfma_f32_16x16x32_bf16(qf[ds], bf, sacc[ct], 0, 0, 0);
            }
        }

        // ---- causal mask (D layout: row = lkg*4+j, col = lrow) ----
        #pragma unroll
        for (int ct = 0; ct < 4; ++ct) {
            int key = s0 + ct * 16 + lrow;
            #pragma unroll
            for (int j = 0; j < 4; ++j) {
                int gqr = q0 + wid * 16 + lkg * 4 + j;
                if (key > gqr) sacc[ct][j] = -3e38f;
            }
        }

        // ---- online softmax (16-lane butterfly per q-row) ----
        float corr[4];
        #pragma unroll
        for (int j = 0; j < 4; ++j) {
            float tm = fmaxf(fmaxf(sacc[0][j], sacc[1][j]), fmaxf(sacc[2][j], sacc[3][j]));
            #pragma unroll
            for (int w = 1; w < 16; w <<= 1) tm = fmaxf(tm, __shfl_xor(tm, w, 16));
            float mn = fmaxf(mrow[j], tm);
            corr[j] = __expf(mrow[j] - mn);
            mrow[j] = mn;
        }
        float psum[4] = {0.f, 0.f, 0.f, 0.f};
        unsigned short pb[4][4];
        #pragma unroll
        for (int ct = 0; ct < 4; ++ct)
            #pragma unroll
            for (int j = 0; j < 4; ++j) {
                float p = __expf(sacc[ct][j] - mrow[j]);
                psum[j] += p;
                pb[ct][j] = f2bf(p);
            }
        #pragma unroll
        for (int j = 0; j < 4; ++j) {
            float ps = psum[j];
            #pragma unroll
            for (int w = 1; w < 16; w <<= 1) ps += __shfl_xor(ps, w, 16);
            lsum[j] = lsum[j] * corr[j] + ps;
        }
        #pragma unroll
        for (int dt = 0; dt < 8; ++dt)
            #pragma unroll
            for (int j = 0; j < 4; ++j) oacc[dt][j] *= corr[j];

        // ---- P -> per-wave LDS (bf16, swizzled); wave-local, no barrier ----
        #pragma unroll
        for (int ct = 0; ct < 4; ++ct)
            #pragma unroll
            for (int j = 0; j < 4; ++j) {
                int r = lkg * 4 + j, c = ct * 16 + lrow;
                int byte = ((r * 64 + c) * 2) ^ ((r & 7) << 4);
                *(unsigned short*)((char*)Ps[wid] + byte) = pb[ct][j];
            }

        // ---- O += P V : 2 k-steps x 8 dv-tiles ----
        #pragma unroll
        for (int ks = 0; ks < 2; ++ks) {
            int abyte = ((lrow * 64 + ks * 32 + lkg * 8) * 2) ^ ((lrow & 7) << 4);
            short8v af = *(const short8v*)((char*)Ps[wid] + abyte);
            #pragma unroll
            for (int dt = 0; dt < 8; ++dt) {
                int vrow = dt * 16 + lrow;
                int byte = ((vrow * 64 + ks * 32 + lkg * 8) * 2) ^ ((vrow & 7) << 4);
                short8v bf = *(const short8v*)((char*)Vt + byte);
                oacc[dt] = __builtin_amdgcn_mfma_f32_16x16x32_bf16(af, bf, oacc[dt], 0, 0, 0);
            }
        }
    }

    // ---- epilogue ----
    float inv[4];
    #pragma unroll
    for (int j = 0; j < 4; ++j) inv[j] = 1.0f / lsum[j];
    #pragma unroll
    for (int dt = 0; dt < 8; ++dt)
        #pragma unroll
        for (int j = 0; j < 4; ++j) {
            int grow = q0 + wid * 16 + lkg * 4 + j;
            out[(size_t)grow * 2048 + n * 128 + dt * 16 + lrow] = oacc[dt][j] * inv[j];
        }
}

extern "C" void kernel_launch(void* const* d_in, const int* in_sizes, int n_in,
                              void* d_out, int out_size, void* d_ws, size_t ws_size,
                              hipStream_t stream)
{
    const float* x         = (const float*)d_in[0];
    const int*   positions = (const int*)  d_in[1];
    const float* w_q_a     = (const float*)d_in[2];
    const float* q_a_norm  = (const float*)d_in[3];
    const float* w_q_b     = (const float*)d_in[4];
    const float* w_kv_a    = (const float*)d_in[5];
    const float* kv_a_norm = (const float*)d_in[6];
    const float* w_kv_b    = (const float*)d_in[7];
    const float* w_o       = (const float*)d_in[8];
    float* out = (float*)d_out;

    float* ws       = (float*)d_ws;
    float* q_c      = ws;                               // T*1536
    float* q        = q_c + (size_t)T_TOK * RQ_;        // T*3072
    float* kv       = q   + (size_t)T_TOK * 3072;       // T*576
    float* kvb      = kv  + (size_t)T_TOK * 576;        // T*4096
    float* attn_out = kvb + (size_t)T_TOK * 4096;       // T*2048

    dim3 blk(256);

    // q_c = rmsnorm(x @ w_q_a)
    gemm_f32<<<dim3(RQ_ / 64, T_TOK / 64), blk, 0, stream>>>(
        x, w_q_a, q_c, T_TOK, RQ_, D_MODEL, D_MODEL, RQ_, RQ_);
    rmsnorm_rows<<<T_TOK, blk, 0, stream>>>(q_c, q_a_norm, RQ_);

    // q = q_c @ w_q_b ; rope q_pe
    gemm_f32<<<dim3(3072 / 64, T_TOK / 64), blk, 0, stream>>>(
        q_c, w_q_b, q, T_TOK, 3072, RQ_, RQ_, 3072, 3072);
    rope_q<<<(T_TOK * NHEADS * 32) / 256, blk, 0, stream>>>(q, positions);

    // kv = x @ w_kv_a ; rmsnorm kv_c ; rope k_pe
    gemm_f32<<<dim3(576 / 64, T_TOK / 64), blk, 0, stream>>>(
        x, w_kv_a, kv, T_TOK, 576, D_MODEL, D_MODEL, 576, 576);
    kv_fuse<<<T_TOK, blk, 0, stream>>>(kv, kv_a_norm, positions);

    // kvb = kv_c @ w_kv_b   (A has row stride 576, K = 512)
    gemm_f32<<<dim3(4096 / 64, T_TOK / 64), blk, 0, stream>>>(
        kv, w_kv_b, kvb, T_TOK, 4096, RKV_, 576, 4096, 4096);

    // attention (MFMA flash)
    attn_mfma<<<dim3(T_TOK / QBLK, NHEADS), blk, 0, stream>>>(q, kvb, kv, attn_out);

    // out = attn_out @ w_o
    gemm_f32<<<dim3(D_MODEL / 64, T_TOK / 64), blk, 0, stream>>>(
        attn_out, w_o, out, T_TOK, D_MODEL, NHEADS * DVDIM, 2048, D_MODEL, D_MODEL);
}

// Round 5
// 565.124 us; speedup vs baseline: 13.4184x; 3.0545x over previous
//
#include <hip/hip_runtime.h>
#include <hip/hip_bf16.h>
#include <math.h>

#define T_TOK   2048
#define D_MODEL 2048
#define NHEADS  16
#define RQ_     1536
#define RKV_    512
#define EPS_    1e-6f
#define THETA_  10000.0f

typedef __attribute__((ext_vector_type(8))) short short8v;
typedef __attribute__((ext_vector_type(4))) float f32x4;

__device__ inline unsigned short f2bf(float f) {
    union { float f; unsigned u; } v; v.f = f;
    unsigned r = v.u + 0x7fffu + ((v.u >> 16) & 1u);
    return (unsigned short)(r >> 16);
}

// ---------------- block-wide reduce (256 threads = 4 waves) ----------------
__device__ inline float block_reduce(float v, bool is_max, float* sred) {
    #pragma unroll
    for (int off = 32; off > 0; off >>= 1) {
        float o = __shfl_down(v, off, 64);
        v = is_max ? fmaxf(v, o) : (v + o);
    }
    int tid = threadIdx.x;
    __syncthreads();
    if ((tid & 63) == 0) sred[tid >> 6] = v;
    __syncthreads();
    float r = sred[0];
    #pragma unroll
    for (int w = 1; w < 4; ++w) r = is_max ? fmaxf(r, sred[w]) : (r + sred[w]);
    return r;
}

// ---------------- fp32 -> bf16 elementwise (n4 = n/4) ----------------
__global__ __launch_bounds__(256) void conv_bf16(const float* __restrict__ in,
    unsigned short* __restrict__ out, int n4)
{
    int i = blockIdx.x * 256 + threadIdx.x;
    if (i >= n4) return;
    float4 v = ((const float4*)in)[i];
    ushort4 o;
    o.x = f2bf(v.x); o.y = f2bf(v.y); o.z = f2bf(v.z); o.w = f2bf(v.w);
    ((ushort4*)out)[i] = o;
}

// ------------- fp32 [R][C] -> bf16 transposed [C][R] -------------
__global__ __launch_bounds__(256) void wt_bf16(const float* __restrict__ W,
    unsigned short* __restrict__ Wt, int R, int C)
{
    __shared__ float tile[32][33];
    int c0 = blockIdx.x * 32, r0 = blockIdx.y * 32;
    int tx = threadIdx.x & 31, ty = threadIdx.x >> 5;  // ty 0..7
    #pragma unroll
    for (int i = 0; i < 4; ++i)
        tile[ty + i * 8][tx] = W[(size_t)(r0 + ty + i * 8) * C + c0 + tx];
    __syncthreads();
    #pragma unroll
    for (int i = 0; i < 4; ++i)
        Wt[(size_t)(c0 + ty + i * 8) * R + r0 + tx] = f2bf(tile[tx][ty + i * 8]);
}

// =============== bf16 MFMA GEMM: C[M,N] = A[M,K] * Bt[N,K]^T ===============
// 128x128 tile, BK=64, 4 waves (2x2 quadrants of 64x64 each).
__global__ __launch_bounds__(256) void gemm_bf16(
    const unsigned short* __restrict__ A,   // [M][K] bf16
    const unsigned short* __restrict__ Bt,  // [>=gridX*128][K] bf16
    float* __restrict__ C, int N, int K, int ldc)
{
    __shared__ __align__(16) unsigned short As[128 * 64];
    __shared__ __align__(16) unsigned short Bs[128 * 64];
    const int tid = threadIdx.x;
    const int lane = tid & 63, wid = tid >> 6;
    const int wr = wid >> 1, wc = wid & 1;
    const int lrow = lane & 15, lkg = lane >> 4;
    const int r0 = blockIdx.y * 128, c0 = blockIdx.x * 128;

    f32x4 acc[4][4];
    #pragma unroll
    for (int m = 0; m < 4; ++m)
        #pragma unroll
        for (int n = 0; n < 4; ++n) acc[m][n] = (f32x4)0.f;

    for (int k0 = 0; k0 < K; k0 += 64) {
        __syncthreads();
        #pragma unroll
        for (int pass = 0; pass < 4; ++pass) {
            int u = pass * 256 + tid;          // 16B unit index 0..1023
            int r = u >> 3, cu = u & 7;
            int sw = r * 128 + ((cu ^ (r & 7)) << 4);
            short8v va = *(const short8v*)(A  + (size_t)(r0 + r) * K + k0 + cu * 8);
            *(short8v*)((char*)As + sw) = va;
            short8v vb = *(const short8v*)(Bt + (size_t)(c0 + r) * K + k0 + cu * 8);
            *(short8v*)((char*)Bs + sw) = vb;
        }
        __syncthreads();
        #pragma unroll
        for (int ks = 0; ks < 2; ++ks) {
            short8v af[4], bf[4];
            #pragma unroll
            for (int m = 0; m < 4; ++m) {
                int row = wr * 64 + m * 16 + lrow;
                af[m] = *(const short8v*)((char*)As + row * 128 + (((ks * 4 + lkg) ^ (row & 7)) << 4));
            }
            #pragma unroll
            for (int n = 0; n < 4; ++n) {
                int row = wc * 64 + n * 16 + lrow;
                bf[n] = *(const short8v*)((char*)Bs + row * 128 + (((ks * 4 + lkg) ^ (row & 7)) << 4));
            }
            #pragma unroll
            for (int m = 0; m < 4; ++m)
                #pragma unroll
                for (int n = 0; n < 4; ++n)
                    acc[m][n] = __builtin_amdgcn_mfma_f32_16x16x32_bf16(af[m], bf[n], acc[m][n], 0, 0, 0);
        }
    }
    // D layout: col = lane&15, row = (lane>>4)*4 + j
    #pragma unroll
    for (int m = 0; m < 4; ++m) {
        int grow = r0 + wr * 64 + m * 16 + lkg * 4;
        #pragma unroll
        for (int n = 0; n < 4; ++n) {
            int gcol = c0 + wc * 64 + n * 16 + lrow;
            if (gcol < N) {
                #pragma unroll
                for (int j = 0; j < 4; ++j)
                    C[(size_t)(grow + j) * ldc + gcol] = acc[m][n][j];
            }
        }
    }
}

// ---------------- RMSNorm rows -> bf16 ----------------
__global__ __launch_bounds__(256) void rmsnorm_bf16(const float* __restrict__ y,
    const float* __restrict__ g, unsigned short* __restrict__ o, int width)
{
    __shared__ float sred[4];
    int row = blockIdx.x;
    const float* p = y + (size_t)row * width;
    float ss = 0.f;
    for (int i = threadIdx.x; i < width; i += 256) { float v = p[i]; ss += v * v; }
    ss = block_reduce(ss, false, sred);
    float sc = rsqrtf(ss / (float)width + EPS_);
    for (int i = threadIdx.x; i < width; i += 256)
        o[(size_t)row * width + i] = f2bf(p[i] * sc * g[i]);
}

// -- kv row: rmsnorm first 512 -> bf16 out ; RoPE cols 512..575 fp32 inplace --
__global__ __launch_bounds__(256) void kv_fuse(float* __restrict__ kv,
    const float* __restrict__ g, const int* __restrict__ positions,
    unsigned short* __restrict__ kvcb)
{
    __shared__ float sred[4];
    int row = blockIdx.x;
    float* p = kv + (size_t)row * 576;
    float ss = 0.f;
    for (int i = threadIdx.x; i < 512; i += 256) { float v = p[i]; ss += v * v; }
    ss = block_reduce(ss, false, sred);
    float sc = rsqrtf(ss / 512.0f + EPS_);
    for (int i = threadIdx.x; i < 512; i += 256)
        kvcb[(size_t)row * 512 + i] = f2bf(p[i] * sc * g[i]);
    if (threadIdx.x < 32) {
        int i = threadIdx.x;
        float pos = (float)positions[row];
        float inv = powf(THETA_, -(float)i / 32.0f);
        float ang = pos * inv;
        float c = cosf(ang), s = sinf(ang);
        float x1 = p[512 + i], x2 = p[544 + i];
        p[512 + i] = x1 * c - x2 * s;
        p[544 + i] = x2 * c + x1 * s;
    }
}

// ---------------- RoPE on q_pe, in place ----------------
__global__ __launch_bounds__(256) void rope_q(float* __restrict__ q,
    const int* __restrict__ positions)
{
    int id = blockIdx.x * 256 + threadIdx.x;   // T*N*32 total
    int i = id & 31;
    int n = (id >> 5) & 15;
    int t = id >> 9;
    float* p = q + (size_t)t * 3072 + n * 192 + 128;
    float pos = (float)positions[t];
    float inv = powf(THETA_, -(float)i / 32.0f);
    float ang = pos * inv;
    float c = cosf(ang), s = sinf(ang);
    float x1 = p[i], x2 = p[32 + i];
    p[i]      = x1 * c - x2 * s;
    p[32 + i] = x2 * c + x1 * s;
}

// =================== MFMA flash attention (bf16 out) ===================
#define QBLK  64
#define KVBLK 64

__global__ __launch_bounds__(256) void attn_mfma(
    const float* __restrict__ q,     // [T][16*192]
    const float* __restrict__ kvb,   // [T][16][256] (0:128 k_nope, 128:256 v)
    const float* __restrict__ kv,    // [T][576]     (512:576 k_pe)
    unsigned short* __restrict__ out) // [T][2048] bf16
{
    __shared__ __align__(16) unsigned short Ks[KVBLK * 192];   // 24 KB
    __shared__ __align__(16) unsigned short Vt[128 * KVBLK];   // 16 KB
    __shared__ __align__(16) unsigned short Ps[4][16 * KVBLK]; //  8 KB

    const int qt = blockIdx.x, n = blockIdx.y;
    const int tid = threadIdx.x;
    const int lane = tid & 63, wid = tid >> 6;
    const int lrow = lane & 15;
    const int lkg  = lane >> 4;
    const int q0 = qt * QBLK;
    const float scale = 0.07216878364870323f;  // (128+64)^-0.5

    short8v qf[6];
    {
        const float* qrow = q + (size_t)(q0 + wid * 16 + lrow) * 3072 + n * 192;
        #pragma unroll
        for (int ds = 0; ds < 6; ++ds) {
            int d = ds * 32 + lkg * 8;
            float4 a = *(const float4*)(qrow + d);
            float4 b = *(const float4*)(qrow + d + 4);
            short8v f;
            f[0] = f2bf(a.x * scale); f[1] = f2bf(a.y * scale);
            f[2] = f2bf(a.z * scale); f[3] = f2bf(a.w * scale);
            f[4] = f2bf(b.x * scale); f[5] = f2bf(b.y * scale);
            f[6] = f2bf(b.z * scale); f[7] = f2bf(b.w * scale);
            qf[ds] = f;
        }
    }

    f32x4 oacc[8];
    #pragma unroll
    for (int i = 0; i < 8; ++i) oacc[i] = (f32x4)0.f;
    float mrow[4] = {-3e38f, -3e38f, -3e38f, -3e38f};
    float lsum[4] = {0.f, 0.f, 0.f, 0.f};

    const int ntiles = qt + 1;
    for (int tile = 0; tile < ntiles; ++tile) {
        const int s0 = tile * KVBLK;
        __syncthreads();

        for (int i4 = tid; i4 < 64 * 48; i4 += 256) {
            int row = i4 / 48, c4 = i4 % 48;
            float4 v;
            if (c4 < 32) v = *(const float4*)(kvb + ((size_t)(s0 + row) * 16 + n) * 256 + c4 * 4);
            else         v = *(const float4*)(kv + (size_t)(s0 + row) * 576 + 512 + (c4 - 32) * 4);
            unsigned lo = (unsigned)f2bf(v.x) | ((unsigned)f2bf(v.y) << 16);
            unsigned hi = (unsigned)f2bf(v.z) | ((unsigned)f2bf(v.w) << 16);
            int byte = (row * 192 + c4 * 4) * 2;
            byte ^= (row & 7) << 4;
            *(uint2*)((char*)Ks + byte) = make_uint2(lo, hi);
        }
        for (int i4 = tid; i4 < 64 * 32; i4 += 256) {
            int s = i4 / 32, d4 = (i4 % 32) * 4;
            float4 v = *(const float4*)(kvb + ((size_t)(s0 + s) * 16 + n) * 256 + 128 + d4);
            #pragma unroll
            for (int e = 0; e < 4; ++e) {
                int dv = d4 + e;
                int byte = ((dv * 64 + s) * 2) ^ ((dv & 7) << 4);
                *(unsigned short*)((char*)Vt + byte) = f2bf(((const float*)&v)[e]);
            }
        }
        __syncthreads();

        f32x4 sacc[4];
        #pragma unroll
        for (int ct = 0; ct < 4; ++ct) sacc[ct] = (f32x4)0.f;
        #pragma unroll
        for (int ds = 0; ds < 6; ++ds) {
            #pragma unroll
            for (int ct = 0; ct < 4; ++ct) {
                int krow = ct * 16 + lrow;
                int byte = ((krow * 192 + ds * 32 + lkg * 8) * 2) ^ ((krow & 7) << 4);
                short8v bf = *(const short8v*)((char*)Ks + byte);
                sacc[ct] = __builtin_amdgcn_mfma_f32_16x16x32_bf16(qf[ds], bf, sacc[ct], 0, 0, 0);
            }
        }

        #pragma unroll
        for (int ct = 0; ct < 4; ++ct) {
            int key = s0 + ct * 16 + lrow;
            #pragma unroll
            for (int j = 0; j < 4; ++j) {
                int gqr = q0 + wid * 16 + lkg * 4 + j;
                if (key > gqr) sacc[ct][j] = -3e38f;
            }
        }

        float corr[4];
        #pragma unroll
        for (int j = 0; j < 4; ++j) {
            float tm = fmaxf(fmaxf(sacc[0][j], sacc[1][j]), fmaxf(sacc[2][j], sacc[3][j]));
            #pragma unroll
            for (int w = 1; w < 16; w <<= 1) tm = fmaxf(tm, __shfl_xor(tm, w, 16));
            float mn = fmaxf(mrow[j], tm);
            corr[j] = __expf(mrow[j] - mn);
            mrow[j] = mn;
        }
        float psum[4] = {0.f, 0.f, 0.f, 0.f};
        unsigned short pb[4][4];
        #pragma unroll
        for (int ct = 0; ct < 4; ++ct)
            #pragma unroll
            for (int j = 0; j < 4; ++j) {
                float p = __expf(sacc[ct][j] - mrow[j]);
                psum[j] += p;
                pb[ct][j] = f2bf(p);
            }
        #pragma unroll
        for (int j = 0; j < 4; ++j) {
            float ps = psum[j];
            #pragma unroll
            for (int w = 1; w < 16; w <<= 1) ps += __shfl_xor(ps, w, 16);
            lsum[j] = lsum[j] * corr[j] + ps;
        }
        #pragma unroll
        for (int dt = 0; dt < 8; ++dt)
            #pragma unroll
            for (int j = 0; j < 4; ++j) oacc[dt][j] *= corr[j];

        #pragma unroll
        for (int ct = 0; ct < 4; ++ct)
            #pragma unroll
            for (int j = 0; j < 4; ++j) {
                int r = lkg * 4 + j, c = ct * 16 + lrow;
                int byte = ((r * 64 + c) * 2) ^ ((r & 7) << 4);
                *(unsigned short*)((char*)Ps[wid] + byte) = pb[ct][j];
            }

        #pragma unroll
        for (int ks = 0; ks < 2; ++ks) {
            int abyte = ((lrow * 64 + ks * 32 + lkg * 8) * 2) ^ ((lrow & 7) << 4);
            short8v af = *(const short8v*)((char*)Ps[wid] + abyte);
            #pragma unroll
            for (int dt = 0; dt < 8; ++dt) {
                int vrow = dt * 16 + lrow;
                int byte = ((vrow * 64 + ks * 32 + lkg * 8) * 2) ^ ((vrow & 7) << 4);
                short8v bf = *(const short8v*)((char*)Vt + byte);
                oacc[dt] = __builtin_amdgcn_mfma_f32_16x16x32_bf16(af, bf, oacc[dt], 0, 0, 0);
            }
        }
    }

    float inv[4];
    #pragma unroll
    for (int j = 0; j < 4; ++j) inv[j] = 1.0f / lsum[j];
    #pragma unroll
    for (int dt = 0; dt < 8; ++dt)
        #pragma unroll
        for (int j = 0; j < 4; ++j) {
            int grow = q0 + wid * 16 + lkg * 4 + j;
            out[(size_t)grow * 2048 + n * 128 + dt * 16 + lrow] = f2bf(oacc[dt][j] * inv[j]);
        }
}

extern "C" void kernel_launch(void* const* d_in, const int* in_sizes, int n_in,
                              void* d_out, int out_size, void* d_ws, size_t ws_size,
                              hipStream_t stream)
{
    const float* x         = (const float*)d_in[0];
    const int*   positions = (const int*)  d_in[1];
    const float* w_q_a     = (const float*)d_in[2];
    const float* q_a_norm  = (const float*)d_in[3];
    const float* w_q_b     = (const float*)d_in[4];
    const float* w_kv_a    = (const float*)d_in[5];
    const float* kv_a_norm = (const float*)d_in[6];
    const float* w_kv_b    = (const float*)d_in[7];
    const float* w_o       = (const float*)d_in[8];
    float* out = (float*)d_out;

    // ---- workspace layout (89.7 MB total) ----
    float* q   = (float*)d_ws;                          // 2048*3072
    float* kv  = q  + (size_t)2048 * 3072;              // 2048*576
    float* kvb = kv + (size_t)2048 * 576;               // 2048*4096
    float* q_c = kvb;                                   // alias (2048*1536, dead before kvb)
    unsigned short* q_cb  = (unsigned short*)(kvb + (size_t)2048 * 4096); // 2048*1536
    unsigned short* kv_cb = q_cb  + (size_t)2048 * 1536;                  // 2048*512
    unsigned short* xb    = kv_cb + (size_t)2048 * 512;                   // 2048*2048
    unsigned short* aob   = xb;                         // alias (xb dead before attn)
    unsigned short* wbuf  = xb + (size_t)2048 * 2048;   // 3072*1536 max

    dim3 blk(256);

    // x -> bf16
    conv_bf16<<<(2048 * 2048 / 4 + 255) / 256, blk, 0, stream>>>(x, xb, 2048 * 2048 / 4);

    // G1: q_c = x @ w_q_a   (N=1536, K=2048)
    wt_bf16<<<dim3(1536 / 32, 2048 / 32), blk, 0, stream>>>(w_q_a, wbuf, 2048, 1536);
    gemm_bf16<<<dim3(1536 / 128, 16), blk, 0, stream>>>(xb, wbuf, q_c, 1536, 2048, 1536);
    rmsnorm_bf16<<<2048, blk, 0, stream>>>(q_c, q_a_norm, q_cb, 1536);

    // G2: q = q_cb @ w_q_b  (N=3072, K=1536)
    wt_bf16<<<dim3(3072 / 32, 1536 / 32), blk, 0, stream>>>(w_q_b, wbuf, 1536, 3072);
    gemm_bf16<<<dim3(3072 / 128, 16), blk, 0, stream>>>(q_cb, wbuf, q, 3072, 1536, 3072);
    rope_q<<<(2048 * 16 * 32) / 256, blk, 0, stream>>>(q, positions);

    // G3: kv = x @ w_kv_a   (N=576, K=2048; Bt padded to 640 rows)
    wt_bf16<<<dim3(576 / 32, 2048 / 32), blk, 0, stream>>>(w_kv_a, wbuf, 2048, 576);
    gemm_bf16<<<dim3(5, 16), blk, 0, stream>>>(xb, wbuf, kv, 576, 2048, 576);
    kv_fuse<<<2048, blk, 0, stream>>>(kv, kv_a_norm, positions, kv_cb);

    // G4: kvb = kv_cb @ w_kv_b  (N=4096, K=512)
    wt_bf16<<<dim3(4096 / 32, 512 / 32), blk, 0, stream>>>(w_kv_b, wbuf, 512, 4096);
    gemm_bf16<<<dim3(4096 / 128, 16), blk, 0, stream>>>(kv_cb, wbuf, kvb, 4096, 512, 4096);

    // attention (writes bf16 aob; xb dead now)
    attn_mfma<<<dim3(2048 / QBLK, NHEADS), blk, 0, stream>>>(q, kvb, kv, aob);

    // G5: out = aob @ w_o   (N=2048, K=2048)
    wt_bf16<<<dim3(2048 / 32, 2048 / 32), blk, 0, stream>>>(w_o, wbuf, 2048, 2048);
    gemm_bf16<<<dim3(2048 / 128, 16), blk, 0, stream>>>(aob, wbuf, out, 2048, 2048, 2048);
}

// Round 6
// 385.206 us; speedup vs baseline: 19.6857x; 1.4671x over previous
//
#include <hip/hip_runtime.h>
#include <hip/hip_bf16.h>
#include <math.h>

#define T_TOK   2048
#define NHEADS  16
#define EPS_    1e-6f
#define THETA_  10000.0f

typedef __attribute__((ext_vector_type(8))) short short8v;
typedef __attribute__((ext_vector_type(4))) float f32x4;

__device__ inline unsigned short f2bf(float f) {
    union { float f; unsigned u; } v; v.f = f;
    unsigned r = v.u + 0x7fffu + ((v.u >> 16) & 1u);
    return (unsigned short)(r >> 16);
}

// ---------------- block-wide reduce (256 threads = 4 waves) ----------------
__device__ inline float block_reduce(float v, bool is_max, float* sred) {
    #pragma unroll
    for (int off = 32; off > 0; off >>= 1) {
        float o = __shfl_down(v, off, 64);
        v = is_max ? fmaxf(v, o) : (v + o);
    }
    int tid = threadIdx.x;
    __syncthreads();
    if ((tid & 63) == 0) sred[tid >> 6] = v;
    __syncthreads();
    float r = sred[0];
    #pragma unroll
    for (int w = 1; w < 4; ++w) r = is_max ? fmaxf(r, sred[w]) : (r + sred[w]);
    return r;
}

// ---------------- fp32 -> bf16 elementwise (n4 = n/4) ----------------
__global__ __launch_bounds__(256) void conv_bf16(const float* __restrict__ in,
    unsigned short* __restrict__ out, int n4)
{
    int i = blockIdx.x * 256 + threadIdx.x;
    if (i >= n4) return;
    float4 v = ((const float4*)in)[i];
    ushort4 o;
    o.x = f2bf(v.x); o.y = f2bf(v.y); o.z = f2bf(v.z); o.w = f2bf(v.w);
    ((ushort4*)out)[i] = o;
}

// ------------- fp32 [R][C] -> bf16 transposed [C][R] -------------
__global__ __launch_bounds__(256) void wt_bf16(const float* __restrict__ W,
    unsigned short* __restrict__ Wt, int R, int C)
{
    __shared__ float tile[32][33];
    int c0 = blockIdx.x * 32, r0 = blockIdx.y * 32;
    int tx = threadIdx.x & 31, ty = threadIdx.x >> 5;  // ty 0..7
    #pragma unroll
    for (int i = 0; i < 4; ++i)
        tile[ty + i * 8][tx] = W[(size_t)(r0 + ty + i * 8) * C + c0 + tx];
    __syncthreads();
    #pragma unroll
    for (int i = 0; i < 4; ++i)
        Wt[(size_t)(c0 + ty + i * 8) * R + r0 + tx] = f2bf(tile[tx][ty + i * 8]);
}

// =============== bf16 MFMA GEMM: C[M,N] = A[M,K] * Bt[N,K]^T ===============
// 128x128 tile, BK=64, 4 waves (2x2 quadrants of 64x64 each).
template<bool BF16OUT>
__global__ __launch_bounds__(256) void gemm_bf16(
    const unsigned short* __restrict__ A,   // [M][K] bf16
    const unsigned short* __restrict__ Bt,  // [>=gridX*128][K] bf16
    void* __restrict__ Cv, int N, int K, int ldc)
{
    __shared__ __align__(16) unsigned short As[128 * 64];
    __shared__ __align__(16) unsigned short Bs[128 * 64];
    const int tid = threadIdx.x;
    const int lane = tid & 63, wid = tid >> 6;
    const int wr = wid >> 1, wc = wid & 1;
    const int lrow = lane & 15, lkg = lane >> 4;
    const int r0 = blockIdx.y * 128, c0 = blockIdx.x * 128;

    f32x4 acc[4][4];
    #pragma unroll
    for (int m = 0; m < 4; ++m)
        #pragma unroll
        for (int n = 0; n < 4; ++n) acc[m][n] = (f32x4)0.f;

    for (int k0 = 0; k0 < K; k0 += 64) {
        __syncthreads();
        #pragma unroll
        for (int pass = 0; pass < 4; ++pass) {
            int u = pass * 256 + tid;          // 16B unit index 0..1023
            int r = u >> 3, cu = u & 7;
            int sw = r * 128 + ((cu ^ (r & 7)) << 4);
            short8v va = *(const short8v*)(A  + (size_t)(r0 + r) * K + k0 + cu * 8);
            *(short8v*)((char*)As + sw) = va;
            short8v vb = *(const short8v*)(Bt + (size_t)(c0 + r) * K + k0 + cu * 8);
            *(short8v*)((char*)Bs + sw) = vb;
        }
        __syncthreads();
        #pragma unroll
        for (int ks = 0; ks < 2; ++ks) {
            short8v af[4], bf[4];
            #pragma unroll
            for (int m = 0; m < 4; ++m) {
                int row = wr * 64 + m * 16 + lrow;
                af[m] = *(const short8v*)((char*)As + row * 128 + (((ks * 4 + lkg) ^ (row & 7)) << 4));
            }
            #pragma unroll
            for (int n = 0; n < 4; ++n) {
                int row = wc * 64 + n * 16 + lrow;
                bf[n] = *(const short8v*)((char*)Bs + row * 128 + (((ks * 4 + lkg) ^ (row & 7)) << 4));
            }
            #pragma unroll
            for (int m = 0; m < 4; ++m)
                #pragma unroll
                for (int n = 0; n < 4; ++n)
                    acc[m][n] = __builtin_amdgcn_mfma_f32_16x16x32_bf16(af[m], bf[n], acc[m][n], 0, 0, 0);
        }
    }
    // D layout: col = lane&15, row = (lane>>4)*4 + j
    #pragma unroll
    for (int m = 0; m < 4; ++m) {
        int grow = r0 + wr * 64 + m * 16 + lkg * 4;
        #pragma unroll
        for (int n = 0; n < 4; ++n) {
            int gcol = c0 + wc * 64 + n * 16 + lrow;
            if (gcol < N) {
                #pragma unroll
                for (int j = 0; j < 4; ++j) {
                    if (BF16OUT)
                        ((unsigned short*)Cv)[(size_t)(grow + j) * ldc + gcol] = f2bf(acc[m][n][j]);
                    else
                        ((float*)Cv)[(size_t)(grow + j) * ldc + gcol] = acc[m][n][j];
                }
            }
        }
    }
}

// ---------------- RMSNorm rows -> bf16 ----------------
__global__ __launch_bounds__(256) void rmsnorm_bf16(const float* __restrict__ y,
    const float* __restrict__ g, unsigned short* __restrict__ o, int width)
{
    __shared__ float sred[4];
    int row = blockIdx.x;
    const float* p = y + (size_t)row * width;
    float ss = 0.f;
    for (int i = threadIdx.x; i < width; i += 256) { float v = p[i]; ss += v * v; }
    ss = block_reduce(ss, false, sred);
    float sc = rsqrtf(ss / (float)width + EPS_);
    for (int i = threadIdx.x; i < width; i += 256)
        o[(size_t)row * width + i] = f2bf(p[i] * sc * g[i]);
}

// -- kv row: rmsnorm first 512 -> bf16 out ; RoPE cols 512..575 fp32 inplace --
__global__ __launch_bounds__(256) void kv_fuse(float* __restrict__ kv,
    const float* __restrict__ g, const int* __restrict__ positions,
    unsigned short* __restrict__ kvcb)
{
    __shared__ float sred[4];
    int row = blockIdx.x;
    float* p = kv + (size_t)row * 576;
    float ss = 0.f;
    for (int i = threadIdx.x; i < 512; i += 256) { float v = p[i]; ss += v * v; }
    ss = block_reduce(ss, false, sred);
    float sc = rsqrtf(ss / 512.0f + EPS_);
    for (int i = threadIdx.x; i < 512; i += 256)
        kvcb[(size_t)row * 512 + i] = f2bf(p[i] * sc * g[i]);
    if (threadIdx.x < 32) {
        int i = threadIdx.x;
        float pos = (float)positions[row];
        float inv = powf(THETA_, -(float)i / 32.0f);
        float ang = pos * inv;
        float c = cosf(ang), s = sinf(ang);
        float x1 = p[512 + i], x2 = p[544 + i];
        p[512 + i] = x1 * c - x2 * s;
        p[544 + i] = x2 * c + x1 * s;
    }
}

// -------- RoPE + scale + bf16 pack of q: [T][3072] f32 -> [T][16][192] bf16 --------
__global__ __launch_bounds__(192) void rope_qb(const float* __restrict__ q,
    const int* __restrict__ positions, unsigned short* __restrict__ qb)
{
    int t = blockIdx.x, d = threadIdx.x;
    const float scale = 0.07216878364870323f;  // (128+64)^-0.5
    float c = 1.f, s = 0.f;
    if (d >= 128) {
        int i = (d - 128) & 31;
        float pos = (float)positions[t];
        float inv = powf(THETA_, -(float)i / 32.0f);
        float ang = pos * inv;
        c = cosf(ang); s = sinf(ang);
    }
    #pragma unroll 4
    for (int n = 0; n < 16; ++n) {
        const float* p = q + (size_t)t * 3072 + n * 192;
        float v;
        if (d < 128)      v = p[d];
        else if (d < 160) v = p[d] * c - p[d + 32] * s;
        else              v = p[d] * c + p[d - 32] * s;
        qb[((size_t)t * 16 + n) * 192 + d] = f2bf(v * scale);
    }
}

// -------- K cache: [16][T][192] bf16 = k_nope (from kvb bf16) + roped k_pe --------
__global__ __launch_bounds__(256) void repack_k(const unsigned short* __restrict__ kvbb,
    const float* __restrict__ kv, unsigned short* __restrict__ Kc)
{
    int t = blockIdx.x, tid = threadIdx.x;
    int n = tid >> 4;
    int c8 = tid & 15;
    short8v v = *(const short8v*)(kvbb + ((size_t)t * 16 + n) * 256 + c8 * 8);
    *(short8v*)(Kc + ((size_t)n * 2048 + t) * 192 + c8 * 8) = v;
    int i4 = (tid & 15) * 4;
    float4 p = *(const float4*)(kv + (size_t)t * 576 + 512 + i4);
    ushort4 o; o.x = f2bf(p.x); o.y = f2bf(p.y); o.z = f2bf(p.z); o.w = f2bf(p.w);
    *(ushort4*)(Kc + ((size_t)n * 2048 + t) * 192 + 128 + i4) = o;
}

// -------- V^T cache: [16][128][T] bf16, LDS-tiled 64x64 transpose --------
__global__ __launch_bounds__(256) void repack_vt(const unsigned short* __restrict__ kvbb,
    unsigned short* __restrict__ Vtc)
{
    __shared__ unsigned short tile[64][72];
    int t0 = blockIdx.x * 64;
    int n = blockIdx.y >> 1, dv0 = (blockIdx.y & 1) * 64;
    int tid = threadIdx.x;
    for (int u = tid; u < 512; u += 256) {
        int t = u >> 3, c8 = u & 7;
        short8v v = *(const short8v*)(kvbb + ((size_t)(t0 + t) * 16 + n) * 256 + 128 + dv0 + c8 * 8);
        *(short8v*)(&tile[t][c8 * 8]) = v;
    }
    __syncthreads();
    for (int u = tid; u < 512; u += 256) {
        int dv = u & 63, t8 = u >> 6;
        short8v v;
        #pragma unroll
        for (int e = 0; e < 8; ++e) v[e] = (short)tile[t8 * 8 + e][dv];
        *(short8v*)(Vtc + ((size_t)n * 128 + dv0 + dv) * 2048 + t0 + t8 * 8) = v;
    }
}

// =================== MFMA flash attention (packed bf16 inputs) ===================
#define QBLK  64
#define KVBLK 64

__global__ __launch_bounds__(256) void attn_mfma(
    const unsigned short* __restrict__ qb,   // [T][16][192] bf16 (scale folded)
    const unsigned short* __restrict__ Kc,   // [16][T][192] bf16
    const unsigned short* __restrict__ Vtc,  // [16][128][T] bf16
    unsigned short* __restrict__ out)        // [T][2048] bf16
{
    __shared__ __align__(16) unsigned short Ks[KVBLK * 192];   // 24 KB
    __shared__ __align__(16) unsigned short Vt[128 * KVBLK];   // 16 KB
    __shared__ __align__(16) unsigned short Ps[4][16 * KVBLK]; //  8 KB

    // balanced remap: co-resident blocks lin and lin+256 have qt + qt' = 31
    const int lin = blockIdx.x;
    int qt, n;
    if (lin < 256) { qt = lin & 31; n = lin >> 5; }
    else           { qt = 31 - (lin & 31); n = 8 + ((lin - 256) >> 5); }

    const int tid = threadIdx.x;
    const int lane = tid & 63, wid = tid >> 6;
    const int lrow = lane & 15;
    const int lkg  = lane >> 4;
    const int q0 = qt * QBLK;

    // ---- Q fragments (direct bf16 loads) ----
    short8v qf[6];
    {
        const unsigned short* qrow = qb + ((size_t)(q0 + wid * 16 + lrow) * 16 + n) * 192;
        #pragma unroll
        for (int ds = 0; ds < 6; ++ds)
            qf[ds] = *(const short8v*)(qrow + ds * 32 + lkg * 8);
    }

    f32x4 oacc[8];
    #pragma unroll
    for (int i = 0; i < 8; ++i) oacc[i] = (f32x4)0.f;
    float mrow[4] = {-3e38f, -3e38f, -3e38f, -3e38f};
    float lsum[4] = {0.f, 0.f, 0.f, 0.f};

    const int ntiles = qt + 1;
    for (int tile = 0; tile < ntiles; ++tile) {
        const int s0 = tile * KVBLK;
        __syncthreads();

        // ---- stage K tile: 64 rows x 192 bf16, vector copies ----
        for (int i = tid; i < 1536; i += 256) {
            int row = i / 24, c8 = i % 24;
            short8v v = *(const short8v*)(Kc + ((size_t)n * 2048 + s0 + row) * 192 + c8 * 8);
            int byte = (row * 384 + c8 * 16) ^ ((row & 7) << 4);
            *(short8v*)((char*)Ks + byte) = v;
        }
        // ---- stage V^T tile: 128 rows x 64 bf16, vector copies ----
        for (int i = tid; i < 1024; i += 256) {
            int dv = i >> 3, c8 = i & 7;
            short8v v = *(const short8v*)(Vtc + ((size_t)n * 128 + dv) * 2048 + s0 + c8 * 8);
            int byte = (dv * 128 + c8 * 16) ^ ((dv & 7) << 4);
            *(short8v*)((char*)Vt + byte) = v;
        }
        __syncthreads();

        // ---- S = Q K^T ----
        f32x4 sacc[4];
        #pragma unroll
        for (int ct = 0; ct < 4; ++ct) sacc[ct] = (f32x4)0.f;
        #pragma unroll
        for (int ds = 0; ds < 6; ++ds) {
            #pragma unroll
            for (int ct = 0; ct < 4; ++ct) {
                int krow = ct * 16 + lrow;
                int byte = (krow * 384 + ds * 64 + lkg * 16) ^ ((krow & 7) << 4);
                short8v bf = *(const short8v*)((char*)Ks + byte);
                sacc[ct] = __builtin_amdgcn_mfma_f32_16x16x32_bf16(qf[ds], bf, sacc[ct], 0, 0, 0);
            }
        }

        // ---- causal mask (D layout: row = lkg*4+j, col = lrow) ----
        #pragma unroll
        for (int ct = 0; ct < 4; ++ct) {
            int key = s0 + ct * 16 + lrow;
            #pragma unroll
            for (int j = 0; j < 4; ++j) {
                int gqr = q0 + wid * 16 + lkg * 4 + j;
                if (key > gqr) sacc[ct][j] = -3e38f;
            }
        }

        // ---- online softmax ----
        float corr[4];
        #pragma unroll
        for (int j = 0; j < 4; ++j) {
            float tm = fmaxf(fmaxf(sacc[0][j], sacc[1][j]), fmaxf(sacc[2][j], sacc[3][j]));
            #pragma unroll
            for (int w = 1; w < 16; w <<= 1) tm = fmaxf(tm, __shfl_xor(tm, w, 16));
            float mn = fmaxf(mrow[j], tm);
            corr[j] = __expf(mrow[j] - mn);
            mrow[j] = mn;
        }
        float psum[4] = {0.f, 0.f, 0.f, 0.f};
        unsigned short pb[4][4];
        #pragma unroll
        for (int ct = 0; ct < 4; ++ct)
            #pragma unroll
            for (int j = 0; j < 4; ++j) {
                float p = __expf(sacc[ct][j] - mrow[j]);
                psum[j] += p;
                pb[ct][j] = f2bf(p);
            }
        #pragma unroll
        for (int j = 0; j < 4; ++j) {
            float ps = psum[j];
            #pragma unroll
            for (int w = 1; w < 16; w <<= 1) ps += __shfl_xor(ps, w, 16);
            lsum[j] = lsum[j] * corr[j] + ps;
        }
        #pragma unroll
        for (int dt = 0; dt < 8; ++dt)
            #pragma unroll
            for (int j = 0; j < 4; ++j) oacc[dt][j] *= corr[j];

        // ---- P -> per-wave LDS (wave-local, no barrier) ----
        #pragma unroll
        for (int ct = 0; ct < 4; ++ct)
            #pragma unroll
            for (int j = 0; j < 4; ++j) {
                int r = lkg * 4 + j, c = ct * 16 + lrow;
                int byte = ((r * 64 + c) * 2) ^ ((r & 7) << 4);
                *(unsigned short*)((char*)Ps[wid] + byte) = pb[ct][j];
            }

        // ---- O += P V ----
        #pragma unroll
        for (int ks = 0; ks < 2; ++ks) {
            int abyte = ((lrow * 64 + ks * 32 + lkg * 8) * 2) ^ ((lrow & 7) << 4);
            short8v af = *(const short8v*)((char*)Ps[wid] + abyte);
            #pragma unroll
            for (int dt = 0; dt < 8; ++dt) {
                int vrow = dt * 16 + lrow;
                int byte = ((vrow * 128 + ks * 64 + lkg * 16)) ^ ((vrow & 7) << 4);
                short8v bf = *(const short8v*)((char*)Vt + byte);
                oacc[dt] = __builtin_amdgcn_mfma_f32_16x16x32_bf16(af, bf, oacc[dt], 0, 0, 0);
            }
        }
    }

    // ---- epilogue ----
    float inv[4];
    #pragma unroll
    for (int j = 0; j < 4; ++j) inv[j] = 1.0f / lsum[j];
    #pragma unroll
    for (int dt = 0; dt < 8; ++dt)
        #pragma unroll
        for (int j = 0; j < 4; ++j) {
            int grow = q0 + wid * 16 + lkg * 4 + j;
            out[(size_t)grow * 2048 + n * 128 + dt * 16 + lrow] = f2bf(oacc[dt][j] * inv[j]);
        }
}

extern "C" void kernel_launch(void* const* d_in, const int* in_sizes, int n_in,
                              void* d_out, int out_size, void* d_ws, size_t ws_size,
                              hipStream_t stream)
{
    const float* x         = (const float*)d_in[0];
    const int*   positions = (const int*)  d_in[1];
    const float* w_q_a     = (const float*)d_in[2];
    const float* q_a_norm  = (const float*)d_in[3];
    const float* w_q_b     = (const float*)d_in[4];
    const float* w_kv_a    = (const float*)d_in[5];
    const float* kv_a_norm = (const float*)d_in[6];
    const float* w_kv_b    = (const float*)d_in[7];
    const float* w_o       = (const float*)d_in[8];
    float* out = (float*)d_out;

    // ---- workspace layout (~85.4 MB) ----
    float* q   = (float*)d_ws;                          // 2048*3072 f32 (later Kc/Vtc)
    float* kv  = q + (size_t)2048 * 3072;               // 2048*576 f32
    unsigned short* kvbb = (unsigned short*)(kv + (size_t)2048 * 576); // 2048*4096 bf16
    float* q_c = (float*)kvbb;                          // alias (2048*1536 f32, dead before kvbb)
    unsigned short* q_cb  = kvbb + (size_t)2048 * 4096; // 2048*1536
    unsigned short* kv_cb = q_cb + (size_t)2048 * 1536; // 2048*512
    unsigned short* xb    = kv_cb + (size_t)2048 * 512; // 2048*2048
    unsigned short* aob   = xb;                         // alias (xb dead before attn)
    unsigned short* qb    = xb + (size_t)2048 * 2048;   // 2048*16*192
    unsigned short* wbuf  = qb + (size_t)2048 * 3072;   // 3072*1536 max
    unsigned short* Kc    = (unsigned short*)q;         // 16*2048*192 (q dead after rope_qb)
    unsigned short* Vtc   = Kc + (size_t)16 * 2048 * 192; // 16*128*2048

    dim3 blk(256);

    // x -> bf16
    conv_bf16<<<(2048 * 2048 / 4 + 255) / 256, blk, 0, stream>>>(x, xb, 2048 * 2048 / 4);

    // G1: q_c = x @ w_q_a   (N=1536, K=2048) fp32 out
    wt_bf16<<<dim3(1536 / 32, 2048 / 32), blk, 0, stream>>>(w_q_a, wbuf, 2048, 1536);
    gemm_bf16<false><<<dim3(1536 / 128, 16), blk, 0, stream>>>(xb, wbuf, q_c, 1536, 2048, 1536);
    rmsnorm_bf16<<<2048, blk, 0, stream>>>(q_c, q_a_norm, q_cb, 1536);

    // G2: q = q_cb @ w_q_b  (N=3072, K=1536) fp32 out; then rope+pack -> qb
    wt_bf16<<<dim3(3072 / 32, 1536 / 32), blk, 0, stream>>>(w_q_b, wbuf, 1536, 3072);
    gemm_bf16<false><<<dim3(3072 / 128, 16), blk, 0, stream>>>(q_cb, wbuf, q, 3072, 1536, 3072);
    rope_qb<<<2048, dim3(192), 0, stream>>>(q, positions, qb);   // q dead after

    // G3: kv = x @ w_kv_a   (N=576, K=2048) fp32 out
    wt_bf16<<<dim3(576 / 32, 2048 / 32), blk, 0, stream>>>(w_kv_a, wbuf, 2048, 576);
    gemm_bf16<false><<<dim3(5, 16), blk, 0, stream>>>(xb, wbuf, kv, 576, 2048, 576);
    kv_fuse<<<2048, blk, 0, stream>>>(kv, kv_a_norm, positions, kv_cb);

    // G4: kvbb = kv_cb @ w_kv_b  (N=4096, K=512) bf16 out
    wt_bf16<<<dim3(4096 / 32, 512 / 32), blk, 0, stream>>>(w_kv_b, wbuf, 512, 4096);
    gemm_bf16<true><<<dim3(4096 / 128, 16), blk, 0, stream>>>(kv_cb, wbuf, kvbb, 4096, 512, 4096);

    // repack K and V^T caches (overwrites q's space)
    repack_k<<<2048, blk, 0, stream>>>(kvbb, kv, Kc);
    repack_vt<<<dim3(32, 32), blk, 0, stream>>>(kvbb, Vtc);

    // attention (balanced remap grid)
    attn_mfma<<<512, blk, 0, stream>>>(qb, Kc, Vtc, aob);

    // G5: out = aob @ w_o   (N=2048, K=2048) fp32 out
    wt_bf16<<<dim3(2048 / 32, 2048 / 32), blk, 0, stream>>>(w_o, wbuf, 2048, 2048);
    gemm_bf16<false><<<dim3(2048 / 128, 16), blk, 0, stream>>>(aob, wbuf, out, 2048, 2048, 2048);
}

// Round 7
// 325.866 us; speedup vs baseline: 23.2705x; 1.1821x over previous
//
#include <hip/hip_runtime.h>
#include <hip/hip_bf16.h>
#include <math.h>

#define T_TOK   2048
#define NHEADS  16
#define EPS_    1e-6f
#define THETA_  10000.0f

typedef __attribute__((ext_vector_type(8))) short short8v;
typedef __attribute__((ext_vector_type(4))) float f32x4;

__device__ inline unsigned short f2bf(float f) {
    union { float f; unsigned u; } v; v.f = f;
    unsigned r = v.u + 0x7fffu + ((v.u >> 16) & 1u);
    return (unsigned short)(r >> 16);
}

// async global->LDS, 16B per lane; LDS dest is wave-uniform base + lane*16
__device__ __forceinline__ void gload16(const unsigned short* src, unsigned short* lds) {
    __builtin_amdgcn_global_load_lds(
        (const __attribute__((address_space(1))) unsigned int*)src,
        (__attribute__((address_space(3))) unsigned int*)lds, 16, 0, 0);
}

// ---------------- block-wide reduce (256 threads = 4 waves) ----------------
__device__ inline float block_reduce(float v, bool is_max, float* sred) {
    #pragma unroll
    for (int off = 32; off > 0; off >>= 1) {
        float o = __shfl_down(v, off, 64);
        v = is_max ? fmaxf(v, o) : (v + o);
    }
    int tid = threadIdx.x;
    __syncthreads();
    if ((tid & 63) == 0) sred[tid >> 6] = v;
    __syncthreads();
    float r = sred[0];
    #pragma unroll
    for (int w = 1; w < 4; ++w) r = is_max ? fmaxf(r, sred[w]) : (r + sred[w]);
    return r;
}

// ---------------- fp32 -> bf16 elementwise (n4 = n/4) ----------------
__global__ __launch_bounds__(256) void conv_bf16(const float* __restrict__ in,
    unsigned short* __restrict__ out, int n4)
{
    int i = blockIdx.x * 256 + threadIdx.x;
    if (i >= n4) return;
    float4 v = ((const float4*)in)[i];
    ushort4 o;
    o.x = f2bf(v.x); o.y = f2bf(v.y); o.z = f2bf(v.z); o.w = f2bf(v.w);
    ((ushort4*)out)[i] = o;
}

// ------------- fp32 [R][C] -> bf16 transposed [C][R] -------------
__global__ __launch_bounds__(256) void wt_bf16(const float* __restrict__ W,
    unsigned short* __restrict__ Wt, int R, int C)
{
    __shared__ float tile[32][33];
    int c0 = blockIdx.x * 32, r0 = blockIdx.y * 32;
    int tx = threadIdx.x & 31, ty = threadIdx.x >> 5;  // ty 0..7
    #pragma unroll
    for (int i = 0; i < 4; ++i)
        tile[ty + i * 8][tx] = W[(size_t)(r0 + ty + i * 8) * C + c0 + tx];
    __syncthreads();
    #pragma unroll
    for (int i = 0; i < 4; ++i)
        Wt[(size_t)(c0 + ty + i * 8) * R + r0 + tx] = f2bf(tile[tx][ty + i * 8]);
}

// =============== bf16 MFMA GEMM: C[M,N] = A[M,K] * Bt[N,K]^T ===============
// 128x128 tile, BK=64, 4 waves (2x2 quadrants of 64x64 each).
template<bool BF16OUT>
__global__ __launch_bounds__(256) void gemm_bf16(
    const unsigned short* __restrict__ A,   // [M][K] bf16
    const unsigned short* __restrict__ Bt,  // [>=gridX*128][K] bf16
    void* __restrict__ Cv, int N, int K, int ldc)
{
    __shared__ __align__(16) unsigned short As[128 * 64];
    __shared__ __align__(16) unsigned short Bs[128 * 64];
    const int tid = threadIdx.x;
    const int lane = tid & 63, wid = tid >> 6;
    const int wr = wid >> 1, wc = wid & 1;
    const int lrow = lane & 15, lkg = lane >> 4;
    const int r0 = blockIdx.y * 128, c0 = blockIdx.x * 128;

    f32x4 acc[4][4];
    #pragma unroll
    for (int m = 0; m < 4; ++m)
        #pragma unroll
        for (int n = 0; n < 4; ++n) acc[m][n] = (f32x4)0.f;

    for (int k0 = 0; k0 < K; k0 += 64) {
        __syncthreads();
        #pragma unroll
        for (int pass = 0; pass < 4; ++pass) {
            int u = pass * 256 + tid;          // 16B unit index 0..1023
            int r = u >> 3, cu = u & 7;
            int sw = r * 128 + ((cu ^ (r & 7)) << 4);
            short8v va = *(const short8v*)(A  + (size_t)(r0 + r) * K + k0 + cu * 8);
            *(short8v*)((char*)As + sw) = va;
            short8v vb = *(const short8v*)(Bt + (size_t)(c0 + r) * K + k0 + cu * 8);
            *(short8v*)((char*)Bs + sw) = vb;
        }
        __syncthreads();
        #pragma unroll
        for (int ks = 0; ks < 2; ++ks) {
            short8v af[4], bf[4];
            #pragma unroll
            for (int m = 0; m < 4; ++m) {
                int row = wr * 64 + m * 16 + lrow;
                af[m] = *(const short8v*)((char*)As + row * 128 + (((ks * 4 + lkg) ^ (row & 7)) << 4));
            }
            #pragma unroll
            for (int n = 0; n < 4; ++n) {
                int row = wc * 64 + n * 16 + lrow;
                bf[n] = *(const short8v*)((char*)Bs + row * 128 + (((ks * 4 + lkg) ^ (row & 7)) << 4));
            }
            #pragma unroll
            for (int m = 0; m < 4; ++m)
                #pragma unroll
                for (int n = 0; n < 4; ++n)
                    acc[m][n] = __builtin_amdgcn_mfma_f32_16x16x32_bf16(af[m], bf[n], acc[m][n], 0, 0, 0);
        }
    }
    // D layout: col = lane&15, row = (lane>>4)*4 + j
    #pragma unroll
    for (int m = 0; m < 4; ++m) {
        int grow = r0 + wr * 64 + m * 16 + lkg * 4;
        #pragma unroll
        for (int n = 0; n < 4; ++n) {
            int gcol = c0 + wc * 64 + n * 16 + lrow;
            if (gcol < N) {
                #pragma unroll
                for (int j = 0; j < 4; ++j) {
                    if (BF16OUT)
                        ((unsigned short*)Cv)[(size_t)(grow + j) * ldc + gcol] = f2bf(acc[m][n][j]);
                    else
                        ((float*)Cv)[(size_t)(grow + j) * ldc + gcol] = acc[m][n][j];
                }
            }
        }
    }
}

// ---------------- RMSNorm rows -> bf16 ----------------
__global__ __launch_bounds__(256) void rmsnorm_bf16(const float* __restrict__ y,
    const float* __restrict__ g, unsigned short* __restrict__ o, int width)
{
    __shared__ float sred[4];
    int row = blockIdx.x;
    const float* p = y + (size_t)row * width;
    float ss = 0.f;
    for (int i = threadIdx.x; i < width; i += 256) { float v = p[i]; ss += v * v; }
    ss = block_reduce(ss, false, sred);
    float sc = rsqrtf(ss / (float)width + EPS_);
    for (int i = threadIdx.x; i < width; i += 256)
        o[(size_t)row * width + i] = f2bf(p[i] * sc * g[i]);
}

// -- kv row: rmsnorm first 512 -> bf16 out ; RoPE cols 512..575 fp32 inplace --
__global__ __launch_bounds__(256) void kv_fuse(float* __restrict__ kv,
    const float* __restrict__ g, const int* __restrict__ positions,
    unsigned short* __restrict__ kvcb)
{
    __shared__ float sred[4];
    int row = blockIdx.x;
    float* p = kv + (size_t)row * 576;
    float ss = 0.f;
    for (int i = threadIdx.x; i < 512; i += 256) { float v = p[i]; ss += v * v; }
    ss = block_reduce(ss, false, sred);
    float sc = rsqrtf(ss / 512.0f + EPS_);
    for (int i = threadIdx.x; i < 512; i += 256)
        kvcb[(size_t)row * 512 + i] = f2bf(p[i] * sc * g[i]);
    if (threadIdx.x < 32) {
        int i = threadIdx.x;
        float pos = (float)positions[row];
        float inv = powf(THETA_, -(float)i / 32.0f);
        float ang = pos * inv;
        float c = cosf(ang), s = sinf(ang);
        float x1 = p[512 + i], x2 = p[544 + i];
        p[512 + i] = x1 * c - x2 * s;
        p[544 + i] = x2 * c + x1 * s;
    }
}

// -------- RoPE + scale + bf16 pack of q: [T][3072] f32 -> [T][16][192] bf16 --------
__global__ __launch_bounds__(192) void rope_qb(const float* __restrict__ q,
    const int* __restrict__ positions, unsigned short* __restrict__ qb)
{
    int t = blockIdx.x, d = threadIdx.x;
    const float scale = 0.07216878364870323f;  // (128+64)^-0.5
    float c = 1.f, s = 0.f;
    if (d >= 128) {
        int i = (d - 128) & 31;
        float pos = (float)positions[t];
        float inv = powf(THETA_, -(float)i / 32.0f);
        float ang = pos * inv;
        c = cosf(ang); s = sinf(ang);
    }
    #pragma unroll 4
    for (int n = 0; n < 16; ++n) {
        const float* p = q + (size_t)t * 3072 + n * 192;
        float v;
        if (d < 128)      v = p[d];
        else if (d < 160) v = p[d] * c - p[d + 32] * s;
        else              v = p[d] * c + p[d - 32] * s;
        qb[((size_t)t * 16 + n) * 192 + d] = f2bf(v * scale);
    }
}

// -------- K cache: [16][T][192] bf16 = k_nope (from kvb bf16) + roped k_pe --------
__global__ __launch_bounds__(256) void repack_k(const unsigned short* __restrict__ kvbb,
    const float* __restrict__ kv, unsigned short* __restrict__ Kc)
{
    int t = blockIdx.x, tid = threadIdx.x;
    int n = tid >> 4;
    int c8 = tid & 15;
    short8v v = *(const short8v*)(kvbb + ((size_t)t * 16 + n) * 256 + c8 * 8);
    *(short8v*)(Kc + ((size_t)n * 2048 + t) * 192 + c8 * 8) = v;
    int i4 = (tid & 15) * 4;
    float4 p = *(const float4*)(kv + (size_t)t * 576 + 512 + i4);
    ushort4 o; o.x = f2bf(p.x); o.y = f2bf(p.y); o.z = f2bf(p.z); o.w = f2bf(p.w);
    *(ushort4*)(Kc + ((size_t)n * 2048 + t) * 192 + 128 + i4) = o;
}

// -------- V^T cache: [16][128][T] bf16, LDS-tiled 64x64 transpose --------
__global__ __launch_bounds__(256) void repack_vt(const unsigned short* __restrict__ kvbb,
    unsigned short* __restrict__ Vtc)
{
    __shared__ unsigned short tile[64][72];
    int t0 = blockIdx.x * 64;
    int n = blockIdx.y >> 1, dv0 = (blockIdx.y & 1) * 64;
    int tid = threadIdx.x;
    for (int u = tid; u < 512; u += 256) {
        int t = u >> 3, c8 = u & 7;
        short8v v = *(const short8v*)(kvbb + ((size_t)(t0 + t) * 16 + n) * 256 + 128 + dv0 + c8 * 8);
        *(short8v*)(&tile[t][c8 * 8]) = v;
    }
    __syncthreads();
    for (int u = tid; u < 512; u += 256) {
        int dv = u & 63, t8 = u >> 6;
        short8v v;
        #pragma unroll
        for (int e = 0; e < 8; ++e) v[e] = (short)tile[t8 * 8 + e][dv];
        *(short8v*)(Vtc + ((size_t)n * 128 + dv0 + dv) * 2048 + t0 + t8 * 8) = v;
    }
}

// =================== MFMA flash attention (async-pipelined) ===================
#define QBLK  64
#define KVBLK 64

__global__ __launch_bounds__(256) void attn_mfma(
    const unsigned short* __restrict__ qb,   // [T][16][192] bf16 (scale folded)
    const unsigned short* __restrict__ Kc,   // [16][T][192] bf16
    const unsigned short* __restrict__ Vtc,  // [16][128][T] bf16
    unsigned short* __restrict__ out)        // [T][2048] bf16
{
    __shared__ __align__(16) unsigned short Ks[2][KVBLK * 192];  // 2x24 KB (dbuf)
    __shared__ __align__(16) unsigned short Vt[128 * KVBLK];     // 16 KB
    __shared__ __align__(16) unsigned short Ps[4][16 * KVBLK];   //  8 KB

    // XCD-locality mapping: head pair per XCD, qt balanced-paired (0,31),(1,30)...
    const int bid = blockIdx.x;
    const int xcd = bid & 7;
    const int j   = bid >> 3;                 // 0..63
    const int n   = xcd * 2 + (j >> 5);
    const int i_  = j & 31;
    const int qt  = (i_ & 1) ? 31 - (i_ >> 1) : (i_ >> 1);

    const int tid = threadIdx.x;
    const int lane = tid & 63, wid = tid >> 6;
    const int lrow = lane & 15;
    const int lkg  = lane >> 4;
    const int q0 = qt * QBLK;

    const unsigned short* Kh = Kc  + (size_t)n * 2048 * 192;
    const unsigned short* Vh = Vtc + (size_t)n * 128 * 2048;

    // ---- Q fragments ----
    short8v qf[6];
    {
        const unsigned short* qrow = qb + ((size_t)(q0 + wid * 16 + lrow) * 16 + n) * 192;
        #pragma unroll
        for (int ds = 0; ds < 6; ++ds)
            qf[ds] = *(const short8v*)(qrow + ds * 32 + lkg * 8);
    }

    f32x4 oacc[8];
    #pragma unroll
    for (int i = 0; i < 8; ++i) oacc[i] = (f32x4)0.f;
    float mrow[4] = {-3e38f, -3e38f, -3e38f, -3e38f};
    float lsum[4] = {0.f, 0.f, 0.f, 0.f};

    const int ntiles = qt + 1;

    // ---- prologue: stage K[0] into Ks[0] (gload_lds, inverse-swizzled src) ----
    #pragma unroll
    for (int p = 0; p < 6; ++p) {
        int u = p * 256 + wid * 64 + lane;       // 0..1535
        int row = u / 24, c8 = u % 24;
        gload16(Kh + (size_t)row * 192 + ((c8 ^ (row & 7)) * 8),
                (unsigned short*)((char*)Ks[0] + (p * 256 + wid * 64) * 16));
    }
    __syncthreads();   // drains vmcnt(0): K[0] staged

    int cur = 0;
    for (int tile = 0; tile < ntiles; ++tile) {
        const int s0 = tile * KVBLK;

        // ---- issue V[tile] staging first (needed at mid-tile barrier) ----
        #pragma unroll
        for (int p = 0; p < 4; ++p) {
            int u = p * 256 + wid * 64 + lane;   // 0..1023
            int dv = u >> 3, c8 = u & 7;
            gload16(Vh + (size_t)dv * 2048 + s0 + ((c8 ^ (dv & 7)) * 8),
                    (unsigned short*)((char*)Vt + (p * 256 + wid * 64) * 16));
        }
        // ---- prefetch K[tile+1] into the other buffer ----
        if (tile + 1 < ntiles) {
            const int s1 = s0 + KVBLK;
            #pragma unroll
            for (int p = 0; p < 6; ++p) {
                int u = p * 256 + wid * 64 + lane;
                int row = u / 24, c8 = u % 24;
                gload16(Kh + (size_t)(s1 + row) * 192 + ((c8 ^ (row & 7)) * 8),
                        (unsigned short*)((char*)Ks[cur ^ 1] + (p * 256 + wid * 64) * 16));
            }
        }

        // ---- S = Q K^T from Ks[cur] ----
        f32x4 sacc[4];
        #pragma unroll
        for (int ct = 0; ct < 4; ++ct) sacc[ct] = (f32x4)0.f;
        __builtin_amdgcn_s_setprio(1);
        #pragma unroll
        for (int ds = 0; ds < 6; ++ds) {
            #pragma unroll
            for (int ct = 0; ct < 4; ++ct) {
                int krow = ct * 16 + lrow;
                int byte = (krow * 384 + ds * 64 + lkg * 16) ^ ((krow & 7) << 4);
                short8v bf = *(const short8v*)((char*)Ks[cur] + byte);
                sacc[ct] = __builtin_amdgcn_mfma_f32_16x16x32_bf16(qf[ds], bf, sacc[ct], 0, 0, 0);
            }
        }
        __builtin_amdgcn_s_setprio(0);

        // ---- causal mask (D layout: row = lkg*4+j, col = lrow) ----
        #pragma unroll
        for (int ct = 0; ct < 4; ++ct) {
            int key = s0 + ct * 16 + lrow;
            #pragma unroll
            for (int jj = 0; jj < 4; ++jj) {
                int gqr = q0 + wid * 16 + lkg * 4 + jj;
                if (key > gqr) sacc[ct][jj] = -3e38f;
            }
        }

        // ---- online softmax ----
        float corr[4];
        #pragma unroll
        for (int jj = 0; jj < 4; ++jj) {
            float tm = fmaxf(fmaxf(sacc[0][jj], sacc[1][jj]), fmaxf(sacc[2][jj], sacc[3][jj]));
            #pragma unroll
            for (int w = 1; w < 16; w <<= 1) tm = fmaxf(tm, __shfl_xor(tm, w, 16));
            float mn = fmaxf(mrow[jj], tm);
            corr[jj] = __expf(mrow[jj] - mn);
            mrow[jj] = mn;
        }
        float psum[4] = {0.f, 0.f, 0.f, 0.f};
        unsigned short pb[4][4];
        #pragma unroll
        for (int ct = 0; ct < 4; ++ct)
            #pragma unroll
            for (int jj = 0; jj < 4; ++jj) {
                float p = __expf(sacc[ct][jj] - mrow[jj]);
                psum[jj] += p;
                pb[ct][jj] = f2bf(p);
            }
        #pragma unroll
        for (int jj = 0; jj < 4; ++jj) {
            float ps = psum[jj];
            #pragma unroll
            for (int w = 1; w < 16; w <<= 1) ps += __shfl_xor(ps, w, 16);
            lsum[jj] = lsum[jj] * corr[jj] + ps;
        }
        #pragma unroll
        for (int dt = 0; dt < 8; ++dt)
            #pragma unroll
            for (int jj = 0; jj < 4; ++jj) oacc[dt][jj] *= corr[jj];

        // ---- P -> per-wave LDS (wave-local) ----
        #pragma unroll
        for (int ct = 0; ct < 4; ++ct)
            #pragma unroll
            for (int jj = 0; jj < 4; ++jj) {
                int r = lkg * 4 + jj, c = ct * 16 + lrow;
                int byte = ((r * 64 + c) * 2) ^ ((r & 7) << 4);
                *(unsigned short*)((char*)Ps[wid] + byte) = pb[ct][jj];
            }

        // mid-tile barrier: drains vmcnt -> V[tile] (and K[tile+1]) staged
        __syncthreads();

        // ---- O += P V ----
        __builtin_amdgcn_s_setprio(1);
        #pragma unroll
        for (int ks = 0; ks < 2; ++ks) {
            int abyte = ((lrow * 64 + ks * 32 + lkg * 8) * 2) ^ ((lrow & 7) << 4);
            short8v af = *(const short8v*)((char*)Ps[wid] + abyte);
            #pragma unroll
            for (int dt = 0; dt < 8; ++dt) {
                int vrow = dt * 16 + lrow;
                int byte = ((vrow * 128 + ks * 64 + lkg * 16)) ^ ((vrow & 7) << 4);
                short8v bf = *(const short8v*)((char*)Vt + byte);
                oacc[dt] = __builtin_amdgcn_mfma_f32_16x16x32_bf16(af, bf, oacc[dt], 0, 0, 0);
            }
        }
        __builtin_amdgcn_s_setprio(0);

        // end-of-tile barrier: all waves done with Vt / Ks[cur] before overwrite
        __syncthreads();
        cur ^= 1;
    }

    // ---- epilogue ----
    float inv[4];
    #pragma unroll
    for (int jj = 0; jj < 4; ++jj) inv[jj] = 1.0f / lsum[jj];
    #pragma unroll
    for (int dt = 0; dt < 8; ++dt)
        #pragma unroll
        for (int jj = 0; jj < 4; ++jj) {
            int grow = q0 + wid * 16 + lkg * 4 + jj;
            out[(size_t)grow * 2048 + n * 128 + dt * 16 + lrow] = f2bf(oacc[dt][jj] * inv[jj]);
        }
}

extern "C" void kernel_launch(void* const* d_in, const int* in_sizes, int n_in,
                              void* d_out, int out_size, void* d_ws, size_t ws_size,
                              hipStream_t stream)
{
    const float* x         = (const float*)d_in[0];
    const int*   positions = (const int*)  d_in[1];
    const float* w_q_a     = (const float*)d_in[2];
    const float* q_a_norm  = (const float*)d_in[3];
    const float* w_q_b     = (const float*)d_in[4];
    const float* w_kv_a    = (const float*)d_in[5];
    const float* kv_a_norm = (const float*)d_in[6];
    const float* w_kv_b    = (const float*)d_in[7];
    const float* w_o       = (const float*)d_in[8];
    float* out = (float*)d_out;

    // ---- workspace layout (~85.4 MB) ----
    float* q   = (float*)d_ws;                          // 2048*3072 f32 (later Kc/Vtc)
    float* kv  = q + (size_t)2048 * 3072;               // 2048*576 f32
    unsigned short* kvbb = (unsigned short*)(kv + (size_t)2048 * 576); // 2048*4096 bf16
    float* q_c = (float*)kvbb;                          // alias (2048*1536 f32, dead before kvbb)
    unsigned short* q_cb  = kvbb + (size_t)2048 * 4096; // 2048*1536
    unsigned short* kv_cb = q_cb + (size_t)2048 * 1536; // 2048*512
    unsigned short* xb    = kv_cb + (size_t)2048 * 512; // 2048*2048
    unsigned short* aob   = xb;                         // alias (xb dead before attn)
    unsigned short* qb    = xb + (size_t)2048 * 2048;   // 2048*16*192
    unsigned short* wbuf  = qb + (size_t)2048 * 3072;   // 3072*1536 max
    unsigned short* Kc    = (unsigned short*)q;         // 16*2048*192 (q dead after rope_qb)
    unsigned short* Vtc   = Kc + (size_t)16 * 2048 * 192; // 16*128*2048

    dim3 blk(256);

    // x -> bf16
    conv_bf16<<<(2048 * 2048 / 4 + 255) / 256, blk, 0, stream>>>(x, xb, 2048 * 2048 / 4);

    // G1: q_c = x @ w_q_a   (N=1536, K=2048) fp32 out
    wt_bf16<<<dim3(1536 / 32, 2048 / 32), blk, 0, stream>>>(w_q_a, wbuf, 2048, 1536);
    gemm_bf16<false><<<dim3(1536 / 128, 16), blk, 0, stream>>>(xb, wbuf, q_c, 1536, 2048, 1536);
    rmsnorm_bf16<<<2048, blk, 0, stream>>>(q_c, q_a_norm, q_cb, 1536);

    // G2: q = q_cb @ w_q_b  (N=3072, K=1536) fp32 out; then rope+pack -> qb
    wt_bf16<<<dim3(3072 / 32, 1536 / 32), blk, 0, stream>>>(w_q_b, wbuf, 1536, 3072);
    gemm_bf16<false><<<dim3(3072 / 128, 16), blk, 0, stream>>>(q_cb, wbuf, q, 3072, 1536, 3072);
    rope_qb<<<2048, dim3(192), 0, stream>>>(q, positions, qb);   // q dead after

    // G3: kv = x @ w_kv_a   (N=576, K=2048) fp32 out
    wt_bf16<<<dim3(576 / 32, 2048 / 32), blk, 0, stream>>>(w_kv_a, wbuf, 2048, 576);
    gemm_bf16<false><<<dim3(5, 16), blk, 0, stream>>>(xb, wbuf, kv, 576, 2048, 576);
    kv_fuse<<<2048, blk, 0, stream>>>(kv, kv_a_norm, positions, kv_cb);

    // G4: kvbb = kv_cb @ w_kv_b  (N=4096, K=512) bf16 out
    wt_bf16<<<dim3(4096 / 32, 512 / 32), blk, 0, stream>>>(w_kv_b, wbuf, 512, 4096);
    gemm_bf16<true><<<dim3(4096 / 128, 16), blk, 0, stream>>>(kv_cb, wbuf, kvbb, 4096, 512, 4096);

    // repack K and V^T caches (overwrites q's space)
    repack_k<<<2048, blk, 0, stream>>>(kvbb, kv, Kc);
    repack_vt<<<dim3(32, 32), blk, 0, stream>>>(kvbb, Vtc);

    // attention (XCD-local mapping, async-pipelined staging)
    attn_mfma<<<512, blk, 0, stream>>>(qb, Kc, Vtc, aob);

    // G5: out = aob @ w_o   (N=2048, K=2048) fp32 out
    wt_bf16<<<dim3(2048 / 32, 2048 / 32), blk, 0, stream>>>(w_o, wbuf, 2048, 2048);
    gemm_bf16<false><<<dim3(2048 / 128, 16), blk, 0, stream>>>(aob, wbuf, out, 2048, 2048, 2048);
}

// Round 8
// 295.786 us; speedup vs baseline: 25.6370x; 1.1017x over previous
//
#include <hip/hip_runtime.h>
#include <hip/hip_bf16.h>
#include <math.h>

#define T_TOK   2048
#define NHEADS  16
#define EPS_    1e-6f
#define THETA_  10000.0f

typedef __attribute__((ext_vector_type(8))) short short8v;
typedef __attribute__((ext_vector_type(4))) float f32x4;

__device__ inline unsigned short f2bf(float f) {
    union { float f; unsigned u; } v; v.f = f;
    unsigned r = v.u + 0x7fffu + ((v.u >> 16) & 1u);
    return (unsigned short)(r >> 16);
}

// async global->LDS, 16B per lane; LDS dest is wave-uniform base + lane*16
__device__ __forceinline__ void gload16(const unsigned short* src, unsigned short* lds) {
    __builtin_amdgcn_global_load_lds(
        (const __attribute__((address_space(1))) unsigned int*)src,
        (__attribute__((address_space(3))) unsigned int*)lds, 16, 0, 0);
}

// ---------------- block-wide reduce (256 threads = 4 waves) ----------------
__device__ inline float block_reduce(float v, bool is_max, float* sred) {
    #pragma unroll
    for (int off = 32; off > 0; off >>= 1) {
        float o = __shfl_down(v, off, 64);
        v = is_max ? fmaxf(v, o) : (v + o);
    }
    int tid = threadIdx.x;
    __syncthreads();
    if ((tid & 63) == 0) sred[tid >> 6] = v;
    __syncthreads();
    float r = sred[0];
    #pragma unroll
    for (int w = 1; w < 4; ++w) r = is_max ? fmaxf(r, sred[w]) : (r + sred[w]);
    return r;
}

// ---------------- fp32 -> bf16 elementwise (n4 = n/4) ----------------
__global__ __launch_bounds__(256) void conv_bf16(const float* __restrict__ in,
    unsigned short* __restrict__ out, int n4)
{
    int i = blockIdx.x * 256 + threadIdx.x;
    if (i >= n4) return;
    float4 v = ((const float4*)in)[i];
    ushort4 o;
    o.x = f2bf(v.x); o.y = f2bf(v.y); o.z = f2bf(v.z); o.w = f2bf(v.w);
    ((ushort4*)out)[i] = o;
}

// ------------- fp32 [R][C] -> bf16 transposed [C][R] -------------
__global__ __launch_bounds__(256) void wt_bf16(const float* __restrict__ W,
    unsigned short* __restrict__ Wt, int R, int C)
{
    __shared__ float tile[32][33];
    int c0 = blockIdx.x * 32, r0 = blockIdx.y * 32;
    int tx = threadIdx.x & 31, ty = threadIdx.x >> 5;  // ty 0..7
    #pragma unroll
    for (int i = 0; i < 4; ++i)
        tile[ty + i * 8][tx] = W[(size_t)(r0 + ty + i * 8) * C + c0 + tx];
    __syncthreads();
    #pragma unroll
    for (int i = 0; i < 4; ++i)
        Wt[(size_t)(c0 + ty + i * 8) * R + r0 + tx] = f2bf(tile[tx][ty + i * 8]);
}

// =============== bf16 MFMA GEMM: C[M,N] = A[M,K] * Bt[N,K]^T ===============
// 128x128 tile, BK=64, 4 waves; global_load_lds staging + double buffer.
template<bool BF16OUT>
__global__ __launch_bounds__(256) void gemm_bf16(
    const unsigned short* __restrict__ A,   // [M][K] bf16
    const unsigned short* __restrict__ Bt,  // [>=gridX*128][K] bf16
    void* __restrict__ Cv, int N, int K, int ldc)
{
    __shared__ __align__(16) unsigned short As[2][128 * 64];
    __shared__ __align__(16) unsigned short Bs[2][128 * 64];
    const int tid = threadIdx.x;
    const int lane = tid & 63, wid = tid >> 6;
    const int wr = wid >> 1, wc = wid & 1;
    const int lrow = lane & 15, lkg = lane >> 4;
    const int r0 = blockIdx.y * 128, c0 = blockIdx.x * 128;

    f32x4 acc[4][4];
    #pragma unroll
    for (int m = 0; m < 4; ++m)
        #pragma unroll
        for (int n = 0; n < 4; ++n) acc[m][n] = (f32x4)0.f;

    // per-pass staging: unit u = p*256+tid -> row r=u>>3, chunk cu=u&7
    // global src is inverse-swizzled; LDS dest linear (wave-uniform base).
    #define STAGE_GEMM(buf, k0)                                                   \
        {   _Pragma("unroll")                                                     \
            for (int p = 0; p < 4; ++p) {                                         \
                int u = p * 256 + tid;                                            \
                int r = u >> 3, cu = u & 7;                                       \
                int dst = (p * 256 + wid * 64) * 8;                               \
                gload16(A  + (size_t)(r0 + r) * K + (k0) + ((cu ^ (r & 7)) << 3), \
                        As[buf] + dst);                                           \
                gload16(Bt + (size_t)(c0 + r) * K + (k0) + ((cu ^ (r & 7)) << 3), \
                        Bs[buf] + dst);                                           \
            }                                                                     \
        }

    STAGE_GEMM(0, 0)
    __syncthreads();

    const int nkt = K >> 6;
    int buf = 0;
    for (int kt = 0; kt < nkt; ++kt) {
        if (kt + 1 < nkt) STAGE_GEMM(buf ^ 1, (kt + 1) << 6)
        #pragma unroll
        for (int ks = 0; ks < 2; ++ks) {
            short8v af[4], bf[4];
            #pragma unroll
            for (int m = 0; m < 4; ++m) {
                int row = wr * 64 + m * 16 + lrow;
                af[m] = *(const short8v*)((char*)As[buf] + row * 128 + (((ks * 4 + lkg) ^ (row & 7)) << 4));
            }
            #pragma unroll
            for (int n = 0; n < 4; ++n) {
                int row = wc * 64 + n * 16 + lrow;
                bf[n] = *(const short8v*)((char*)Bs[buf] + row * 128 + (((ks * 4 + lkg) ^ (row & 7)) << 4));
            }
            __builtin_amdgcn_s_setprio(1);
            #pragma unroll
            for (int m = 0; m < 4; ++m)
                #pragma unroll
                for (int n = 0; n < 4; ++n)
                    acc[m][n] = __builtin_amdgcn_mfma_f32_16x16x32_bf16(af[m], bf[n], acc[m][n], 0, 0, 0);
            __builtin_amdgcn_s_setprio(0);
        }
        __syncthreads();   // drains vmcnt: next tile staged; buf reads done
        buf ^= 1;
    }
    #undef STAGE_GEMM

    // D layout: col = lane&15, row = (lane>>4)*4 + j
    #pragma unroll
    for (int m = 0; m < 4; ++m) {
        int grow = r0 + wr * 64 + m * 16 + lkg * 4;
        #pragma unroll
        for (int n = 0; n < 4; ++n) {
            int gcol = c0 + wc * 64 + n * 16 + lrow;
            if (gcol < N) {
                #pragma unroll
                for (int j = 0; j < 4; ++j) {
                    if (BF16OUT)
                        ((unsigned short*)Cv)[(size_t)(grow + j) * ldc + gcol] = f2bf(acc[m][n][j]);
                    else
                        ((float*)Cv)[(size_t)(grow + j) * ldc + gcol] = acc[m][n][j];
                }
            }
        }
    }
}

// ---------------- RMSNorm rows -> bf16 ----------------
__global__ __launch_bounds__(256) void rmsnorm_bf16(const float* __restrict__ y,
    const float* __restrict__ g, unsigned short* __restrict__ o, int width)
{
    __shared__ float sred[4];
    int row = blockIdx.x;
    const float* p = y + (size_t)row * width;
    float ss = 0.f;
    for (int i = threadIdx.x; i < width; i += 256) { float v = p[i]; ss += v * v; }
    ss = block_reduce(ss, false, sred);
    float sc = rsqrtf(ss / (float)width + EPS_);
    for (int i = threadIdx.x; i < width; i += 256)
        o[(size_t)row * width + i] = f2bf(p[i] * sc * g[i]);
}

// -- kv row: rmsnorm first 512 -> bf16 out ; RoPE cols 512..575 fp32 inplace --
__global__ __launch_bounds__(256) void kv_fuse(float* __restrict__ kv,
    const float* __restrict__ g, const int* __restrict__ positions,
    unsigned short* __restrict__ kvcb)
{
    __shared__ float sred[4];
    int row = blockIdx.x;
    float* p = kv + (size_t)row * 576;
    float ss = 0.f;
    for (int i = threadIdx.x; i < 512; i += 256) { float v = p[i]; ss += v * v; }
    ss = block_reduce(ss, false, sred);
    float sc = rsqrtf(ss / 512.0f + EPS_);
    for (int i = threadIdx.x; i < 512; i += 256)
        kvcb[(size_t)row * 512 + i] = f2bf(p[i] * sc * g[i]);
    if (threadIdx.x < 32) {
        int i = threadIdx.x;
        float pos = (float)positions[row];
        float inv = powf(THETA_, -(float)i / 32.0f);
        float ang = pos * inv;
        float c = cosf(ang), s = sinf(ang);
        float x1 = p[512 + i], x2 = p[544 + i];
        p[512 + i] = x1 * c - x2 * s;
        p[544 + i] = x2 * c + x1 * s;
    }
}

// -------- RoPE + scale + bf16 pack of q: [T][3072] f32 -> [T][16][192] bf16 --------
__global__ __launch_bounds__(192) void rope_qb(const float* __restrict__ q,
    const int* __restrict__ positions, unsigned short* __restrict__ qb)
{
    int t = blockIdx.x, d = threadIdx.x;
    const float scale = 0.07216878364870323f;  // (128+64)^-0.5
    float c = 1.f, s = 0.f;
    if (d >= 128) {
        int i = (d - 128) & 31;
        float pos = (float)positions[t];
        float inv = powf(THETA_, -(float)i / 32.0f);
        float ang = pos * inv;
        c = cosf(ang); s = sinf(ang);
    }
    #pragma unroll 4
    for (int n = 0; n < 16; ++n) {
        const float* p = q + (size_t)t * 3072 + n * 192;
        float v;
        if (d < 128)      v = p[d];
        else if (d < 160) v = p[d] * c - p[d + 32] * s;
        else              v = p[d] * c + p[d - 32] * s;
        qb[((size_t)t * 16 + n) * 192 + d] = f2bf(v * scale);
    }
}

// -------- K cache: [16][T][192] bf16 = k_nope (from kvb bf16) + roped k_pe --------
__global__ __launch_bounds__(256) void repack_k(const unsigned short* __restrict__ kvbb,
    const float* __restrict__ kv, unsigned short* __restrict__ Kc)
{
    int t = blockIdx.x, tid = threadIdx.x;
    int n = tid >> 4;
    int c8 = tid & 15;
    short8v v = *(const short8v*)(kvbb + ((size_t)t * 16 + n) * 256 + c8 * 8);
    *(short8v*)(Kc + ((size_t)n * 2048 + t) * 192 + c8 * 8) = v;
    int i4 = (tid & 15) * 4;
    float4 p = *(const float4*)(kv + (size_t)t * 576 + 512 + i4);
    ushort4 o; o.x = f2bf(p.x); o.y = f2bf(p.y); o.z = f2bf(p.z); o.w = f2bf(p.w);
    *(ushort4*)(Kc + ((size_t)n * 2048 + t) * 192 + 128 + i4) = o;
}

// -------- V^T cache: [16][128][T] bf16, LDS-tiled 64x64 transpose --------
__global__ __launch_bounds__(256) void repack_vt(const unsigned short* __restrict__ kvbb,
    unsigned short* __restrict__ Vtc)
{
    __shared__ unsigned short tile[64][72];
    int t0 = blockIdx.x * 64;
    int n = blockIdx.y >> 1, dv0 = (blockIdx.y & 1) * 64;
    int tid = threadIdx.x;
    for (int u = tid; u < 512; u += 256) {
        int t = u >> 3, c8 = u & 7;
        short8v v = *(const short8v*)(kvbb + ((size_t)(t0 + t) * 16 + n) * 256 + 128 + dv0 + c8 * 8);
        *(short8v*)(&tile[t][c8 * 8]) = v;
    }
    __syncthreads();
    for (int u = tid; u < 512; u += 256) {
        int dv = u & 63, t8 = u >> 6;
        short8v v;
        #pragma unroll
        for (int e = 0; e < 8; ++e) v[e] = (short)tile[t8 * 8 + e][dv];
        *(short8v*)(Vtc + ((size_t)n * 128 + dv0 + dv) * 2048 + t0 + t8 * 8) = v;
    }
}

// =================== MFMA flash attention (balanced 2-job blocks) ===================
#define QBLK  64
#define KVBLK 64

__global__ __launch_bounds__(256) void attn_mfma(
    const unsigned short* __restrict__ qb,   // [T][16][192] bf16 (scale folded)
    const unsigned short* __restrict__ Kc,   // [16][T][192] bf16
    const unsigned short* __restrict__ Vtc,  // [16][128][T] bf16
    unsigned short* __restrict__ out)        // [T][2048] bf16
{
    __shared__ __align__(16) unsigned short Ks[2][KVBLK * 192];  // 2x24 KB (dbuf)
    __shared__ __align__(16) unsigned short Vt[128 * KVBLK];     // 16 KB
    __shared__ __align__(16) unsigned short Ps[4][16 * KVBLK];   //  8 KB

    // 256 blocks; each does jobs (qt=p, n) then (qt=31-p, n): exactly 33 tiles.
    const int bid = blockIdx.x;
    const int xcd = bid & 7;
    const int m_  = bid >> 3;                 // 0..31
    const int n   = xcd * 2 + (m_ >> 4);
    const int p_  = m_ & 15;

    const int tid = threadIdx.x;
    const int lane = tid & 63, wid = tid >> 6;
    const int lrow = lane & 15;
    const int lkg  = lane >> 4;

    const unsigned short* Kh = Kc  + (size_t)n * 2048 * 192;
    const unsigned short* Vh = Vtc + (size_t)n * 128 * 2048;

    for (int job = 0; job < 2; ++job) {
        const int qt = job ? (31 - p_) : p_;
        const int q0 = qt * QBLK;

        // ---- Q fragments ----
        short8v qf[6];
        {
            const unsigned short* qrow = qb + ((size_t)(q0 + wid * 16 + lrow) * 16 + n) * 192;
            #pragma unroll
            for (int ds = 0; ds < 6; ++ds)
                qf[ds] = *(const short8v*)(qrow + ds * 32 + lkg * 8);
        }

        f32x4 oacc[8];
        #pragma unroll
        for (int i = 0; i < 8; ++i) oacc[i] = (f32x4)0.f;
        float mrow[4] = {-3e38f, -3e38f, -3e38f, -3e38f};
        float lsum[4] = {0.f, 0.f, 0.f, 0.f};

        const int ntiles = qt + 1;

        // ---- prologue: stage K[0] into Ks[0] ----
        #pragma unroll
        for (int p = 0; p < 6; ++p) {
            int u = p * 256 + wid * 64 + lane;       // 0..1535
            int row = u / 24, c8 = u % 24;
            gload16(Kh + (size_t)row * 192 + ((c8 ^ (row & 7)) * 8),
                    (unsigned short*)((char*)Ks[0] + (p * 256 + wid * 64) * 16));
        }
        __syncthreads();   // drains vmcnt(0): K[0] staged

        int cur = 0;
        for (int tile = 0; tile < ntiles; ++tile) {
            const int s0 = tile * KVBLK;

            // ---- issue V[tile] staging (drained at mid-tile barrier) ----
            #pragma unroll
            for (int p = 0; p < 4; ++p) {
                int u = p * 256 + wid * 64 + lane;   // 0..1023
                int dv = u >> 3, c8 = u & 7;
                gload16(Vh + (size_t)dv * 2048 + s0 + ((c8 ^ (dv & 7)) * 8),
                        (unsigned short*)((char*)Vt + (p * 256 + wid * 64) * 16));
            }
            // ---- prefetch K[tile+1] ----
            if (tile + 1 < ntiles) {
                const int s1 = s0 + KVBLK;
                #pragma unroll
                for (int p = 0; p < 6; ++p) {
                    int u = p * 256 + wid * 64 + lane;
                    int row = u / 24, c8 = u % 24;
                    gload16(Kh + (size_t)(s1 + row) * 192 + ((c8 ^ (row & 7)) * 8),
                            (unsigned short*)((char*)Ks[cur ^ 1] + (p * 256 + wid * 64) * 16));
                }
            }

            // ---- S = Q K^T from Ks[cur] ----
            f32x4 sacc[4];
            #pragma unroll
            for (int ct = 0; ct < 4; ++ct) sacc[ct] = (f32x4)0.f;
            __builtin_amdgcn_s_setprio(1);
            #pragma unroll
            for (int ds = 0; ds < 6; ++ds) {
                #pragma unroll
                for (int ct = 0; ct < 4; ++ct) {
                    int krow = ct * 16 + lrow;
                    int byte = (krow * 384 + ds * 64 + lkg * 16) ^ ((krow & 7) << 4);
                    short8v bf = *(const short8v*)((char*)Ks[cur] + byte);
                    sacc[ct] = __builtin_amdgcn_mfma_f32_16x16x32_bf16(qf[ds], bf, sacc[ct], 0, 0, 0);
                }
            }
            __builtin_amdgcn_s_setprio(0);

            // ---- causal mask ----
            #pragma unroll
            for (int ct = 0; ct < 4; ++ct) {
                int key = s0 + ct * 16 + lrow;
                #pragma unroll
                for (int jj = 0; jj < 4; ++jj) {
                    int gqr = q0 + wid * 16 + lkg * 4 + jj;
                    if (key > gqr) sacc[ct][jj] = -3e38f;
                }
            }

            // ---- online softmax ----
            float corr[4];
            #pragma unroll
            for (int jj = 0; jj < 4; ++jj) {
                float tm = fmaxf(fmaxf(sacc[0][jj], sacc[1][jj]), fmaxf(sacc[2][jj], sacc[3][jj]));
                #pragma unroll
                for (int w = 1; w < 16; w <<= 1) tm = fmaxf(tm, __shfl_xor(tm, w, 16));
                float mn = fmaxf(mrow[jj], tm);
                corr[jj] = __expf(mrow[jj] - mn);
                mrow[jj] = mn;
            }
            float psum[4] = {0.f, 0.f, 0.f, 0.f};
            unsigned short pb[4][4];
            #pragma unroll
            for (int ct = 0; ct < 4; ++ct)
                #pragma unroll
                for (int jj = 0; jj < 4; ++jj) {
                    float p = __expf(sacc[ct][jj] - mrow[jj]);
                    psum[jj] += p;
                    pb[ct][jj] = f2bf(p);
                }
            #pragma unroll
            for (int jj = 0; jj < 4; ++jj) {
                float ps = psum[jj];
                #pragma unroll
                for (int w = 1; w < 16; w <<= 1) ps += __shfl_xor(ps, w, 16);
                lsum[jj] = lsum[jj] * corr[jj] + ps;
            }
            #pragma unroll
            for (int dt = 0; dt < 8; ++dt)
                #pragma unroll
                for (int jj = 0; jj < 4; ++jj) oacc[dt][jj] *= corr[jj];

            // ---- P -> per-wave LDS ----
            #pragma unroll
            for (int ct = 0; ct < 4; ++ct)
                #pragma unroll
                for (int jj = 0; jj < 4; ++jj) {
                    int r = lkg * 4 + jj, c = ct * 16 + lrow;
                    int byte = ((r * 64 + c) * 2) ^ ((r & 7) << 4);
                    *(unsigned short*)((char*)Ps[wid] + byte) = pb[ct][jj];
                }

            // mid-tile barrier: drains vmcnt -> V[tile] (and K[tile+1]) staged
            __syncthreads();

            // ---- O += P V ----
            __builtin_amdgcn_s_setprio(1);
            #pragma unroll
            for (int ks = 0; ks < 2; ++ks) {
                int abyte = ((lrow * 64 + ks * 32 + lkg * 8) * 2) ^ ((lrow & 7) << 4);
                short8v af = *(const short8v*)((char*)Ps[wid] + abyte);
                #pragma unroll
                for (int dt = 0; dt < 8; ++dt) {
                    int vrow = dt * 16 + lrow;
                    int byte = ((vrow * 128 + ks * 64 + lkg * 16)) ^ ((vrow & 7) << 4);
                    short8v bf = *(const short8v*)((char*)Vt + byte);
                    oacc[dt] = __builtin_amdgcn_mfma_f32_16x16x32_bf16(af, bf, oacc[dt], 0, 0, 0);
                }
            }
            __builtin_amdgcn_s_setprio(0);

            __syncthreads();   // all waves done with Vt / Ks[cur]
            cur ^= 1;
        }

        // ---- epilogue ----
        float inv[4];
        #pragma unroll
        for (int jj = 0; jj < 4; ++jj) inv[jj] = 1.0f / lsum[jj];
        #pragma unroll
        for (int dt = 0; dt < 8; ++dt)
            #pragma unroll
            for (int jj = 0; jj < 4; ++jj) {
                int grow = q0 + wid * 16 + lkg * 4 + jj;
                out[(size_t)grow * 2048 + n * 128 + dt * 16 + lrow] = f2bf(oacc[dt][jj] * inv[jj]);
            }
    }
}

extern "C" void kernel_launch(void* const* d_in, const int* in_sizes, int n_in,
                              void* d_out, int out_size, void* d_ws, size_t ws_size,
                              hipStream_t stream)
{
    const float* x         = (const float*)d_in[0];
    const int*   positions = (const int*)  d_in[1];
    const float* w_q_a     = (const float*)d_in[2];
    const float* q_a_norm  = (const float*)d_in[3];
    const float* w_q_b     = (const float*)d_in[4];
    const float* w_kv_a    = (const float*)d_in[5];
    const float* kv_a_norm = (const float*)d_in[6];
    const float* w_kv_b    = (const float*)d_in[7];
    const float* w_o       = (const float*)d_in[8];
    float* out = (float*)d_out;

    // ---- workspace layout (~85.4 MB) ----
    float* q   = (float*)d_ws;                          // 2048*3072 f32 (later Kc/Vtc)
    float* kv  = q + (size_t)2048 * 3072;               // 2048*576 f32
    unsigned short* kvbb = (unsigned short*)(kv + (size_t)2048 * 576); // 2048*4096 bf16
    float* q_c = (float*)kvbb;                          // alias (2048*1536 f32, dead before kvbb)
    unsigned short* q_cb  = kvbb + (size_t)2048 * 4096; // 2048*1536
    unsigned short* kv_cb = q_cb + (size_t)2048 * 1536; // 2048*512
    unsigned short* xb    = kv_cb + (size_t)2048 * 512; // 2048*2048
    unsigned short* aob   = xb;                         // alias (xb dead before attn)
    unsigned short* qb    = xb + (size_t)2048 * 2048;   // 2048*16*192
    unsigned short* wbuf  = qb + (size_t)2048 * 3072;   // 3072*1536 max
    unsigned short* Kc    = (unsigned short*)q;         // 16*2048*192 (q dead after rope_qb)
    unsigned short* Vtc   = Kc + (size_t)16 * 2048 * 192; // 16*128*2048

    dim3 blk(256);

    // x -> bf16
    conv_bf16<<<(2048 * 2048 / 4 + 255) / 256, blk, 0, stream>>>(x, xb, 2048 * 2048 / 4);

    // G1: q_c = x @ w_q_a   (N=1536, K=2048) fp32 out
    wt_bf16<<<dim3(1536 / 32, 2048 / 32), blk, 0, stream>>>(w_q_a, wbuf, 2048, 1536);
    gemm_bf16<false><<<dim3(1536 / 128, 16), blk, 0, stream>>>(xb, wbuf, q_c, 1536, 2048, 1536);
    rmsnorm_bf16<<<2048, blk, 0, stream>>>(q_c, q_a_norm, q_cb, 1536);

    // G2: q = q_cb @ w_q_b  (N=3072, K=1536) fp32 out; then rope+pack -> qb
    wt_bf16<<<dim3(3072 / 32, 1536 / 32), blk, 0, stream>>>(w_q_b, wbuf, 1536, 3072);
    gemm_bf16<false><<<dim3(3072 / 128, 16), blk, 0, stream>>>(q_cb, wbuf, q, 3072, 1536, 3072);
    rope_qb<<<2048, dim3(192), 0, stream>>>(q, positions, qb);   // q dead after

    // G3: kv = x @ w_kv_a   (N=576, K=2048) fp32 out
    wt_bf16<<<dim3(576 / 32, 2048 / 32), blk, 0, stream>>>(w_kv_a, wbuf, 2048, 576);
    gemm_bf16<false><<<dim3(5, 16), blk, 0, stream>>>(xb, wbuf, kv, 576, 2048, 576);
    kv_fuse<<<2048, blk, 0, stream>>>(kv, kv_a_norm, positions, kv_cb);

    // G4: kvbb = kv_cb @ w_kv_b  (N=4096, K=512) bf16 out
    wt_bf16<<<dim3(4096 / 32, 512 / 32), blk, 0, stream>>>(w_kv_b, wbuf, 512, 4096);
    gemm_bf16<true><<<dim3(4096 / 128, 16), blk, 0, stream>>>(kv_cb, wbuf, kvbb, 4096, 512, 4096);

    // repack K and V^T caches (overwrites q's space)
    repack_k<<<2048, blk, 0, stream>>>(kvbb, kv, Kc);
    repack_vt<<<dim3(32, 32), blk, 0, stream>>>(kvbb, Vtc);

    // attention (256 balanced 2-job blocks, XCD-local heads)
    attn_mfma<<<256, blk, 0, stream>>>(qb, Kc, Vtc, aob);

    // G5: out = aob @ w_o   (N=2048, K=2048) fp32 out
    wt_bf16<<<dim3(2048 / 32, 2048 / 32), blk, 0, stream>>>(w_o, wbuf, 2048, 2048);
    gemm_bf16<false><<<dim3(2048 / 128, 16), blk, 0, stream>>>(aob, wbuf, out, 2048, 2048, 2048);
}